// Round 1
// baseline (383.798 us; speedup 1.0000x reference)
//
#include <hip/hip_runtime.h>
#include <math.h>

#define NN 20000
#define EE 320000
#define ETOT 340000   // EE + NN self-loops
#define NHEADS 8
#define HID 64
#define HCV 512       // NHEADS*HID
#define IND 128
#define OUTD 128
#define NEG_SLOPE 0.2f

typedef __attribute__((ext_vector_type(8))) _Float16 half8;
typedef __attribute__((ext_vector_type(4))) _Float16 half4;
typedef __attribute__((ext_vector_type(4))) float floatx4;

// ---------------- prep: W cvt + x cvt + w1 projection + zero cnt ----------------
__device__ __forceinline__ void cvt_one(const float* W, _Float16* T, int idx, int K, int N) {
    int k = idx / N, n = idx - k * N;
    T[(size_t)n * K + k] = (_Float16)W[idx];
}

#define S1 (IND * HCV)
#define S2 (HCV * HCV)
#define S3 (HCV * OUTD)
#define STOT (S1 + S2 + S3)
#define XTOT (NN * IND)
__global__ void prep_kernel(const float* __restrict__ W1, const float* __restrict__ W2,
                            const float* __restrict__ W3, const float* __restrict__ x,
                            const float* __restrict__ as1, const float* __restrict__ ad1,
                            _Float16* __restrict__ T1, _Float16* __restrict__ T2,
                            _Float16* __restrict__ T3, _Float16* __restrict__ xh,
                            float* __restrict__ w1p, int* __restrict__ cnt) {
    int idx = blockIdx.x * blockDim.x + threadIdx.x;
    if (idx < S1) cvt_one(W1, T1, idx, IND, HCV);
    else if (idx < S1 + S2) cvt_one(W2, T2, idx - S1, HCV, HCV);
    else if (idx < STOT) cvt_one(W3, T3, idx - S1 - S2, HCV, OUTD);
    else if (idx < STOT + NN) cnt[idx - STOT] = 0;
    else if (idx < STOT + NN + XTOT) {
        int j = idx - STOT - NN;
        xh[j] = (_Float16)x[j];
    } else if (idx < STOT + NN + XTOT + IND * 16) {
        int j = idx - STOT - NN - XTOT;
        int c = j >> 4, o = j & 15;
        int hh = o & 7;
        const float* av = (o < 8) ? as1 : ad1;
        float s = 0.f;
        #pragma unroll 8
        for (int jj = 0; jj < HID; jj++)
            s = fmaf(W1[c * HCV + hh * HID + jj], av[hh * HID + jj], s);
        w1p[c * 16 + o] = s;
    }
}

// ---------------- CSR build ----------------

__global__ void count_kernel(const int* __restrict__ ei, int* __restrict__ cnt) {
    int i = blockIdx.x * blockDim.x + threadIdx.x;
    if (i >= ETOT) return;
    int v = (i < EE) ? ei[EE + i] : (i - EE);
    atomicAdd(&cnt[v], 1);
}

#define SCH 20
__global__ __launch_bounds__(1024) void scan_kernel(const int* __restrict__ cnt,
                                                    int* __restrict__ row_ptr,
                                                    int* __restrict__ cursor) {
    __shared__ int wtot[16];
    __shared__ int woff[16];
    int t = threadIdx.x;
    int lane = t & 63;
    int wid = t >> 6;
    int base = t * SCH;
    int vals[SCH];
    int s = 0;
    #pragma unroll
    for (int i = 0; i < SCH; i++) {
        int idx = base + i;
        int v = (idx < NN) ? cnt[idx] : 0;
        vals[i] = v;
        s += v;
    }
    int incl = s;
    #pragma unroll
    for (int off = 1; off < 64; off <<= 1) {
        int u = __shfl_up(incl, off);
        if (lane >= off) incl += u;
    }
    int excl = incl - s;
    if (lane == 63) wtot[wid] = incl;
    __syncthreads();
    if (t == 0) {
        int run = 0;
        #pragma unroll
        for (int j = 0; j < 16; j++) { woff[j] = run; run += wtot[j]; }
        row_ptr[NN] = run;
    }
    __syncthreads();
    int run = woff[wid] + excl;
    #pragma unroll
    for (int i = 0; i < SCH; i++) {
        int idx = base + i;
        if (idx < NN) { row_ptr[idx] = run; cursor[idx] = run; run += vals[i]; }
    }
}

__global__ void fill_kernel(const int* __restrict__ ei, int* __restrict__ cursor,
                            int* __restrict__ csr_src) {
    int i = blockIdx.x * blockDim.x + threadIdx.x;
    if (i >= ETOT) return;
    int u, v;
    if (i < EE) { u = ei[i]; v = ei[EE + i]; }
    else        { u = i - EE; v = i - EE; }
    int pos = atomicAdd(&cursor[v], 1);
    csr_src[pos] = u;
}

// ---------------- layer-1 half-logits from x (thin dot) ----------------
__global__ void al1_thin(const float* __restrict__ x, const float* __restrict__ w1p,
                         float* __restrict__ als, float* __restrict__ ald) {
    int gid = blockIdx.x * blockDim.x + threadIdx.x;
    int node = gid >> 4, o = gid & 15;
    if (node >= NN) return;
    const float* xr = x + (size_t)node * IND;
    float s = 0.f;
    #pragma unroll 4
    for (int c = 0; c < IND; c++)
        s = fmaf(xr[c], w1p[c * 16 + o], s);
    if (o < 8) als[node * 8 + o] = s;
    else       ald[node * 8 + (o - 8)] = s;
}

// ---------------- layer-1 gather: wave per node, per-head agg of x, unroll 4 ----------------
__global__ __launch_bounds__(256) void gather1_kernel(const _Float16* __restrict__ xh,
                                                      const int* __restrict__ row_ptr,
                                                      const int* __restrict__ csr_src,
                                                      const float* __restrict__ als,
                                                      const float* __restrict__ ald,
                                                      _Float16* __restrict__ xagg) {
    int lane = threadIdx.x & 63;
    int v = blockIdx.x * 4 + (threadIdx.x >> 6);
    if (v >= NN) return;
    int hd = lane >> 3;
    int cg = lane & 7;
    float adst = ald[v * NHEADS + hd];
    int s0 = row_ptr[v], s1 = row_ptr[v + 1];
    float acc[16] = {};
    float l = 0.f;
    int i = s0;
    for (; i + 4 <= s1; i += 4) {
        int u[4]; float p[4];
        #pragma unroll
        for (int e = 0; e < 4; e++) u[e] = csr_src[i + e];
        #pragma unroll
        for (int e = 0; e < 4; e++) {
            float t = als[u[e] * NHEADS + hd] + adst;
            t = (t > 0.f) ? t : NEG_SLOPE * t;
            p[e] = __expf(fminf(t, 80.f));
        }
        half8 a[4], b[4];
        #pragma unroll
        for (int e = 0; e < 4; e++) {
            a[e] = *(const half8*)&xh[(size_t)u[e] * IND + cg * 16];
            b[e] = *(const half8*)&xh[(size_t)u[e] * IND + cg * 16 + 8];
        }
        #pragma unroll
        for (int e = 0; e < 4; e++) {
            l += p[e];
            #pragma unroll
            for (int j = 0; j < 8; j++) {
                acc[j]     = fmaf(p[e], (float)a[e][j], acc[j]);
                acc[j + 8] = fmaf(p[e], (float)b[e][j], acc[j + 8]);
            }
        }
    }
    for (; i < s1; i++) {
        int u0 = csr_src[i];
        float t0 = als[u0 * NHEADS + hd] + adst;
        t0 = (t0 > 0.f) ? t0 : NEG_SLOPE * t0;
        float p0 = __expf(fminf(t0, 80.f));
        half8 a0 = *(const half8*)&xh[(size_t)u0 * IND + cg * 16];
        half8 b0 = *(const half8*)&xh[(size_t)u0 * IND + cg * 16 + 8];
        l += p0;
        #pragma unroll
        for (int j = 0; j < 8; j++) {
            acc[j]     = fmaf(p0, (float)a0[j], acc[j]);
            acc[j + 8] = fmaf(p0, (float)b0[j], acc[j + 8]);
        }
    }
    float inv = 1.f / (l + 1e-16f);
    half8 o0, o1;
    #pragma unroll
    for (int j = 0; j < 8; j++) {
        o0[j] = (_Float16)(acc[j] * inv);
        o1[j] = (_Float16)(acc[j + 8] * inv);
    }
    size_t base = (size_t)v * (NHEADS * IND) + hd * IND + cg * 16;
    *(half8*)&xagg[base] = o0;
    *(half8*)&xagg[base + 8] = o1;
}

// ---------------- block-diagonal GEMM (layer 1) ----------------
#define LDK 40
__global__ __launch_bounds__(256) void gemm1_bd(const _Float16* __restrict__ xagg,
                                                const _Float16* __restrict__ Bt,
                                                const float* __restrict__ bias,
                                                _Float16* __restrict__ gact,
                                                int M) {
    __shared__ _Float16 sA[64 * LDK];
    __shared__ _Float16 sB[64 * LDK];
    int tid = threadIdx.x;
    int lane = tid & 63;
    int wv = tid >> 6;
    int m0 = blockIdx.x * 64;
    int h = blockIdx.y;
    int quad = lane >> 4;
    int l15 = lane & 15;
    int arow = tid >> 2;
    int ac4 = tid & 3;

    floatx4 acc[4] = {};

    for (int k0 = 0; k0 < IND; k0 += 32) {
        {
            int gm = m0 + arow;
            int4 va;
            if (gm < M) va = *(const int4*)&xagg[(size_t)gm * (NHEADS * IND) + h * IND + k0 + ac4 * 8];
            else        va = make_int4(0, 0, 0, 0);
            *(int4*)&sA[arow * LDK + ac4 * 8] = va;
            int gn = h * 64 + arow;
            int4 vb = *(const int4*)&Bt[(size_t)gn * IND + k0 + ac4 * 8];
            *(int4*)&sB[arow * LDK + ac4 * 8] = vb;
        }
        __syncthreads();
        half8 a[4], b;
        #pragma unroll
        for (int i = 0; i < 4; i++)
            a[i] = *(const half8*)&sA[(i * 16 + l15) * LDK + quad * 8];
        b = *(const half8*)&sB[(wv * 16 + l15) * LDK + quad * 8];
        #pragma unroll
        for (int i = 0; i < 4; i++)
            acc[i] = __builtin_amdgcn_mfma_f32_16x16x32_f16(a[i], b, acc[i], 0, 0, 0);
        __syncthreads();
    }
    #pragma unroll
    for (int i = 0; i < 4; i++) {
        #pragma unroll
        for (int r = 0; r < 4; r++) {
            int gm = m0 + i * 16 + quad * 4 + r;
            if (gm < M) {
                int col = h * 64 + wv * 16 + l15;
                float o = acc[i][r] + bias[col];
                o = (o > 0.f) ? o : (__expf(o) - 1.f);
                gact[(size_t)gm * HCV + col] = (_Float16)o;
            }
        }
    }
}

// ---------------- MFMA GEMM 64x128 (layer 2): f16, fused al epilogue ----------------
__global__ __launch_bounds__(256) void gemm_l2(const _Float16* __restrict__ A,
                                               const _Float16* __restrict__ Bt,
                                               _Float16* __restrict__ C16,
                                               const float* __restrict__ a_src,
                                               const float* __restrict__ a_dst,
                                               float* __restrict__ als,
                                               float* __restrict__ ald,
                                               int M, int K) {
    __shared__ _Float16 sA[64 * LDK];
    __shared__ _Float16 sB[128 * LDK];
    __shared__ float psum_s[4][64];
    __shared__ float psum_d[4][64];
    int tid = threadIdx.x;
    int lane = tid & 63;
    int wv = tid >> 6;
    int m0 = blockIdx.x * 64, n0 = blockIdx.y * 128;
    int quad = lane >> 4;
    int l15 = lane & 15;
    int arow = tid >> 2;
    int ac4 = tid & 3;

    floatx4 acc[4][2] = {};

    for (int k0 = 0; k0 < K; k0 += 32) {
        {
            int gm = m0 + arow;
            int4 va;
            if (gm < M) va = *(const int4*)&A[(size_t)gm * K + k0 + ac4 * 8];
            else        va = make_int4(0, 0, 0, 0);
            *(int4*)&sA[arow * LDK + ac4 * 8] = va;
            #pragma unroll
            for (int r = 0; r < 2; r++) {
                int gn = n0 + arow + r * 64;
                int4 vb = *(const int4*)&Bt[(size_t)gn * K + k0 + ac4 * 8];
                *(int4*)&sB[(arow + r * 64) * LDK + ac4 * 8] = vb;
            }
        }
        __syncthreads();
        half8 a[4], b[2];
        #pragma unroll
        for (int i = 0; i < 4; i++)
            a[i] = *(const half8*)&sA[(i * 16 + l15) * LDK + quad * 8];
        #pragma unroll
        for (int j = 0; j < 2; j++)
            b[j] = *(const half8*)&sB[(wv * 32 + j * 16 + l15) * LDK + quad * 8];
        #pragma unroll
        for (int i = 0; i < 4; i++)
            #pragma unroll
            for (int j = 0; j < 2; j++)
                acc[i][j] = __builtin_amdgcn_mfma_f32_16x16x32_f16(a[i], b[j], acc[i][j], 0, 0, 0);
        __syncthreads();
    }
    #pragma unroll
    for (int i = 0; i < 4; i++) {
        #pragma unroll
        for (int r = 0; r < 4; r++) {
            int gm = m0 + i * 16 + quad * 4 + r;
            if (gm < M) {
                #pragma unroll
                for (int j = 0; j < 2; j++)
                    C16[(size_t)gm * HCV + n0 + wv * 32 + j * 16 + l15] = (_Float16)acc[i][j][r];
            }
        }
    }
    int h0 = n0 >> 6;
    float as_v[2], ad_v[2];
    #pragma unroll
    for (int j = 0; j < 2; j++) {
        int dim = (wv * 32 + j * 16 + l15) & 63;
        int hh = h0 + (wv >> 1);
        as_v[j] = a_src[hh * HID + dim];
        ad_v[j] = a_dst[hh * HID + dim];
    }
    #pragma unroll
    for (int i = 0; i < 4; i++) {
        #pragma unroll
        for (int r = 0; r < 4; r++) {
            float ps = acc[i][0][r] * as_v[0] + acc[i][1][r] * as_v[1];
            float pd = acc[i][0][r] * ad_v[0] + acc[i][1][r] * ad_v[1];
            #pragma unroll
            for (int off = 1; off <= 8; off <<= 1) {
                ps += __shfl_xor(ps, off);
                pd += __shfl_xor(pd, off);
            }
            if (l15 == 0) {
                int row = i * 16 + quad * 4 + r;
                psum_s[wv][row] = ps;
                psum_d[wv][row] = pd;
            }
        }
    }
    __syncthreads();
    if (tid < 64) {
        int gm = m0 + tid;
        if (gm < M) {
            als[gm * NHEADS + h0]     = psum_s[0][tid] + psum_s[1][tid];
            als[gm * NHEADS + h0 + 1] = psum_s[2][tid] + psum_s[3][tid];
            ald[gm * NHEADS + h0]     = psum_d[0][tid] + psum_d[1][tid];
            ald[gm * NHEADS + h0 + 1] = psum_d[2][tid] + psum_d[3][tid];
        }
    }
}

// ---------------- MFMA GEMM 64x128 (layer 3): f16 C out, fused al3 ----------------
__global__ __launch_bounds__(256) void gemm3(const _Float16* __restrict__ A,
                                             const _Float16* __restrict__ Bt,
                                             _Float16* __restrict__ C16,
                                             const float* __restrict__ a_src,
                                             const float* __restrict__ a_dst,
                                             float* __restrict__ als,
                                             float* __restrict__ ald,
                                             int M, int K) {
    __shared__ _Float16 sA[64 * LDK];
    __shared__ _Float16 sB[128 * LDK];
    __shared__ float psum_s[4][64];
    __shared__ float psum_d[4][64];
    int tid = threadIdx.x;
    int lane = tid & 63;
    int wv = tid >> 6;
    int m0 = blockIdx.x * 64;
    int quad = lane >> 4;
    int l15 = lane & 15;
    int arow = tid >> 2;
    int ac4 = tid & 3;

    floatx4 acc[4][2] = {};

    for (int k0 = 0; k0 < K; k0 += 32) {
        {
            int gm = m0 + arow;
            int4 va;
            if (gm < M) va = *(const int4*)&A[(size_t)gm * K + k0 + ac4 * 8];
            else        va = make_int4(0, 0, 0, 0);
            *(int4*)&sA[arow * LDK + ac4 * 8] = va;
            #pragma unroll
            for (int r = 0; r < 2; r++) {
                int gn = arow + r * 64;
                int4 vb = *(const int4*)&Bt[(size_t)gn * K + k0 + ac4 * 8];
                *(int4*)&sB[(arow + r * 64) * LDK + ac4 * 8] = vb;
            }
        }
        __syncthreads();
        half8 a[4], b[2];
        #pragma unroll
        for (int i = 0; i < 4; i++)
            a[i] = *(const half8*)&sA[(i * 16 + l15) * LDK + quad * 8];
        #pragma unroll
        for (int j = 0; j < 2; j++)
            b[j] = *(const half8*)&sB[(wv * 32 + j * 16 + l15) * LDK + quad * 8];
        #pragma unroll
        for (int i = 0; i < 4; i++)
            #pragma unroll
            for (int j = 0; j < 2; j++)
                acc[i][j] = __builtin_amdgcn_mfma_f32_16x16x32_f16(a[i], b[j], acc[i][j], 0, 0, 0);
        __syncthreads();
    }
    #pragma unroll
    for (int i = 0; i < 4; i++) {
        #pragma unroll
        for (int r = 0; r < 4; r++) {
            int gm = m0 + i * 16 + quad * 4 + r;
            if (gm < M) {
                #pragma unroll
                for (int j = 0; j < 2; j++)
                    C16[(size_t)gm * OUTD + wv * 32 + j * 16 + l15] = (_Float16)acc[i][j][r];
            }
        }
    }
    float as_v[2], ad_v[2];
    #pragma unroll
    for (int j = 0; j < 2; j++) {
        as_v[j] = a_src[wv * 32 + j * 16 + l15];
        ad_v[j] = a_dst[wv * 32 + j * 16 + l15];
    }
    #pragma unroll
    for (int i = 0; i < 4; i++) {
        #pragma unroll
        for (int r = 0; r < 4; r++) {
            float ps = acc[i][0][r] * as_v[0] + acc[i][1][r] * as_v[1];
            float pd = acc[i][0][r] * ad_v[0] + acc[i][1][r] * ad_v[1];
            #pragma unroll
            for (int off = 1; off <= 8; off <<= 1) {
                ps += __shfl_xor(ps, off);
                pd += __shfl_xor(pd, off);
            }
            if (l15 == 0) {
                int row = i * 16 + quad * 4 + r;
                psum_s[wv][row] = ps;
                psum_d[wv][row] = pd;
            }
        }
    }
    __syncthreads();
    if (tid < 64) {
        int gm = m0 + tid;
        if (gm < M) {
            als[gm] = psum_s[0][tid] + psum_s[1][tid] + psum_s[2][tid] + psum_s[3][tid];
            ald[gm] = psum_d[0][tid] + psum_d[1][tid] + psum_d[2][tid] + psum_d[3][tid];
        }
    }
}

// ---------------- layer-2 gather: wave per (node, head), head==XCD affinity ----------------
// Per-head slice of h is NN*64*2B = 2.56 MB (one aligned 128B line per node) -> fits a
// 4 MB XCD L2. head = blockIdx.x & 7 matches the round-robin block->XCD assignment, so
// each XCD only streams its own head slice: compulsory L2 fetch drops 8x vs wave-per-node.
// Within a wave: 4 sub-groups of 16 lanes each handle one edge (8B/lane loads), then
// shfl_xor(16,32) combines. csr reads + output stores are nontemporal to protect the slice.
__global__ __launch_bounds__(256) void gather2_kernel(const _Float16* __restrict__ h,
                                                      const int* __restrict__ row_ptr,
                                                      const int* __restrict__ csr_src,
                                                      const float* __restrict__ als,
                                                      const float* __restrict__ ald,
                                                      const float* __restrict__ bias,
                                                      _Float16* __restrict__ gout) {
    int lane = threadIdx.x & 63;
    int bid = blockIdx.x;
    int hd = bid & 7;                    // head == XCD (round-robin)
    int v = (bid >> 3) * 4 + (threadIdx.x >> 6);
    if (v >= NN) return;
    int sub = lane >> 4;                 // edge slot 0..3
    int l16 = lane & 15;                 // dims l16*4 .. l16*4+3 of this head
    float adst = ald[v * NHEADS + hd];
    int s0 = row_ptr[v], s1 = row_ptr[v + 1];
    const _Float16* hh = h + hd * HID;   // head slice base
    float acc[4] = {};
    float l = 0.f;
    int j = s0;
    for (; j + 8 <= s1; j += 8) {
        int e0 = j + sub, e1 = j + 4 + sub;
        int u0 = __builtin_nontemporal_load(&csr_src[e0]);
        int u1 = __builtin_nontemporal_load(&csr_src[e1]);
        float t0 = als[u0 * NHEADS + hd] + adst;
        float t1 = als[u1 * NHEADS + hd] + adst;
        t0 = (t0 > 0.f) ? t0 : NEG_SLOPE * t0;
        t1 = (t1 > 0.f) ? t1 : NEG_SLOPE * t1;
        float p0 = __expf(fminf(t0, 80.f));
        float p1 = __expf(fminf(t1, 80.f));
        half4 x0 = *(const half4*)&hh[(size_t)u0 * HCV + l16 * 4];
        half4 x1 = *(const half4*)&hh[(size_t)u1 * HCV + l16 * 4];
        l += p0 + p1;
        #pragma unroll
        for (int k = 0; k < 4; k++) {
            acc[k] = fmaf(p0, (float)x0[k], acc[k]);
            acc[k] = fmaf(p1, (float)x1[k], acc[k]);
        }
    }
    for (; j < s1; j += 4) {
        int e = j + sub;
        if (e < s1) {
            int u = __builtin_nontemporal_load(&csr_src[e]);
            float t = als[u * NHEADS + hd] + adst;
            t = (t > 0.f) ? t : NEG_SLOPE * t;
            float p = __expf(fminf(t, 80.f));
            half4 x = *(const half4*)&hh[(size_t)u * HCV + l16 * 4];
            l += p;
            #pragma unroll
            for (int k = 0; k < 4; k++)
                acc[k] = fmaf(p, (float)x[k], acc[k]);
        }
    }
    #pragma unroll
    for (int k = 0; k < 4; k++) {
        acc[k] += __shfl_xor(acc[k], 16);
        acc[k] += __shfl_xor(acc[k], 32);
    }
    l += __shfl_xor(l, 16);
    l += __shfl_xor(l, 32);
    if (sub == 0) {
        float inv = 1.f / (l + 1e-16f);
        half4 hv;
        #pragma unroll
        for (int k = 0; k < 4; k++) {
            float o = fmaf(acc[k], inv, bias[hd * HID + l16 * 4 + k]);
            o = (o > 0.f) ? o : (__expf(o) - 1.f);   // ELU
            hv[k] = (_Float16)o;
        }
        half4* dst = (half4*)&gout[(size_t)v * HCV + hd * HID + l16 * 4];
        __builtin_nontemporal_store(hv, dst);
    }
}

// ---------------- layer-3 gather (fp16 h3 -> fp32 out, with max pass) ----------------
__global__ __launch_bounds__(256) void gather3_kernel(const _Float16* __restrict__ h,
                                                      const int* __restrict__ row_ptr,
                                                      const int* __restrict__ csr_src,
                                                      const float* __restrict__ als,
                                                      const float* __restrict__ ald,
                                                      const float* __restrict__ bias,
                                                      float* __restrict__ out) {
    int lane = threadIdx.x & 63;
    int v = blockIdx.x * 4 + (threadIdx.x >> 6);
    if (v >= NN) return;
    int e_sub = lane >> 4;
    int cg = lane & 15;
    float adst = ald[v];
    int s0 = row_ptr[v], s1 = row_ptr[v + 1];
    float m = -INFINITY;
    for (int i = s0 + e_sub; i < s1; i += 4) {
        int u = csr_src[i];
        float t = als[u] + adst;
        t = (t > 0.f) ? t : NEG_SLOPE * t;
        m = fmaxf(m, t);
    }
    m = fmaxf(m, __shfl_xor(m, 16));
    m = fmaxf(m, __shfl_xor(m, 32));
    float acc[8] = {};
    float l = 0.f;
    for (int i = s0 + e_sub; i < s1; i += 4) {
        int u = csr_src[i];
        float t = als[u] + adst;
        t = (t > 0.f) ? t : NEG_SLOPE * t;
        float p = __expf(t - m);
        half8 x = *(const half8*)&h[(size_t)u * OUTD + cg * 8];
        l += p;
        #pragma unroll
        for (int j = 0; j < 8; j++)
            acc[j] = fmaf(p, (float)x[j], acc[j]);
    }
    l += __shfl_xor(l, 16);
    l += __shfl_xor(l, 32);
    #pragma unroll
    for (int j = 0; j < 8; j++) {
        acc[j] += __shfl_xor(acc[j], 16);
        acc[j] += __shfl_xor(acc[j], 32);
    }
    if (e_sub == 0) {
        float inv = 1.f / (l + 1e-16f);
        float4 o0, o1;
        o0.x = fmaf(acc[0], inv, bias[cg * 8 + 0]);
        o0.y = fmaf(acc[1], inv, bias[cg * 8 + 1]);
        o0.z = fmaf(acc[2], inv, bias[cg * 8 + 2]);
        o0.w = fmaf(acc[3], inv, bias[cg * 8 + 3]);
        o1.x = fmaf(acc[4], inv, bias[cg * 8 + 4]);
        o1.y = fmaf(acc[5], inv, bias[cg * 8 + 5]);
        o1.z = fmaf(acc[6], inv, bias[cg * 8 + 6]);
        o1.w = fmaf(acc[7], inv, bias[cg * 8 + 7]);
        *(float4*)&out[(size_t)v * OUTD + cg * 8] = o0;
        *(float4*)&out[(size_t)v * OUTD + cg * 8 + 4] = o1;
    }
}

// ---------------- launch ----------------

extern "C" void kernel_launch(void* const* d_in, const int* in_sizes, int n_in,
                              void* d_out, int out_size, void* d_ws, size_t ws_size,
                              hipStream_t stream) {
    const float* x     = (const float*)d_in[0];
    const int*   ei    = (const int*)d_in[1];
    const float* W1    = (const float*)d_in[2];
    const float* as1   = (const float*)d_in[3];
    const float* ad1   = (const float*)d_in[4];
    const float* b1    = (const float*)d_in[5];
    const float* W2    = (const float*)d_in[6];
    const float* as2   = (const float*)d_in[7];
    const float* ad2   = (const float*)d_in[8];
    const float* b2    = (const float*)d_in[9];
    const float* W3    = (const float*)d_in[10];
    const float* as3   = (const float*)d_in[11];
    const float* ad3   = (const float*)d_in[12];
    const float* b3    = (const float*)d_in[13];
    float* out = (float*)d_out;

    size_t off = 0;
    auto carve = [&](size_t bytes) {
        void* p = (char*)d_ws + off;
        off += (bytes + 255) & ~(size_t)255;
        return p;
    };
    int* row_ptr   = (int*)carve((NN + 1) * sizeof(int));
    int* cursor    = (int*)carve(NN * sizeof(int));
    int* csr_src   = (int*)carve(ETOT * sizeof(int));
    _Float16* xh   = (_Float16*)carve((size_t)NN * IND * sizeof(_Float16));
    _Float16* xagg = (_Float16*)carve((size_t)NN * NHEADS * IND * sizeof(_Float16));
    _Float16* gact = (_Float16*)carve((size_t)NN * HCV * sizeof(_Float16));
    _Float16* hf16 = (_Float16*)carve((size_t)NN * HCV * sizeof(_Float16));
    _Float16* h3   = (_Float16*)carve((size_t)NN * OUTD * sizeof(_Float16));
    float* als     = (float*)carve((size_t)NN * NHEADS * sizeof(float));
    float* ald     = (float*)carve((size_t)NN * NHEADS * sizeof(float));
    float* w1p     = (float*)carve((size_t)IND * 16 * sizeof(float));
    _Float16* W1T  = (_Float16*)carve((size_t)S1 * sizeof(_Float16));
    _Float16* W2T  = (_Float16*)carve((size_t)S2 * sizeof(_Float16));
    _Float16* W3T  = (_Float16*)carve((size_t)S3 * sizeof(_Float16));
    _Float16* gact2 = xagg;   // aliases xagg (dead after gemm1_bd)
    (void)ws_size; (void)n_in; (void)in_sizes; (void)out_size;

    dim3 blk(256);

    // ---- prep ----
    int prep_n = STOT + NN + XTOT + IND * 16;
    prep_kernel<<<(prep_n + 255) / 256, blk, 0, stream>>>(W1, W2, W3, x, as1, ad1,
        W1T, W2T, W3T, xh, w1p, cursor);

    // ---- CSR build ----
    count_kernel<<<(ETOT + 255) / 256, blk, 0, stream>>>(ei, cursor);
    scan_kernel<<<1, 1024, 0, stream>>>(cursor, row_ptr, cursor);
    fill_kernel<<<(ETOT + 255) / 256, blk, 0, stream>>>(ei, cursor, csr_src);

    int mt64 = (NN + 63) / 64;
    int nwaves_n = (NN + 3) / 4;

    // ---- layer 1: input-side aggregation (wave per node) ----
    al1_thin<<<(NN * 16 + 255) / 256, blk, 0, stream>>>(x, w1p, als, ald);
    gather1_kernel<<<nwaves_n, blk, 0, stream>>>(xh, row_ptr, csr_src, als, ald, xagg);
    gemm1_bd<<<dim3(mt64, NHEADS), blk, 0, stream>>>(xagg, W1T, b1, gact, NN);

    // ---- layer 2: output-side (wave per (node, head), head==XCD) ----
    gemm_l2<<<dim3(mt64, HCV / 128), blk, 0, stream>>>(gact, W2T, hf16, as2, ad2, als, ald, NN, HCV);
    gather2_kernel<<<dim3(nwaves_n * 8), blk, 0, stream>>>(hf16, row_ptr, csr_src, als, ald, b2, gact2);

    // ---- layer 3: output-side, fp16 h3 ----
    gemm3<<<dim3(mt64, 1), blk, 0, stream>>>(gact2, W3T, h3, as3, ad3, als, ald, NN, HCV);
    gather3_kernel<<<nwaves_n, blk, 0, stream>>>(h3, row_ptr, csr_src, als, ald, b3, out);
}

// Round 2
// 332.160 us; speedup vs baseline: 1.1555x; 1.1555x over previous
//
#include <hip/hip_runtime.h>
#include <math.h>

#define NN 20000
#define EE 320000
#define ETOT 340000   // EE + NN self-loops
#define NHEADS 8
#define HID 64
#define HCV 512       // NHEADS*HID
#define IND 128
#define OUTD 128
#define NEG_SLOPE 0.2f

typedef __attribute__((ext_vector_type(8))) _Float16 half8;
typedef __attribute__((ext_vector_type(4))) _Float16 half4;
typedef __attribute__((ext_vector_type(4))) float floatx4;

// ---------------- prep: W cvt + x cvt + w1 projection + zero cnt ----------------
__device__ __forceinline__ void cvt_one(const float* W, _Float16* T, int idx, int K, int N) {
    int k = idx / N, n = idx - k * N;
    T[(size_t)n * K + k] = (_Float16)W[idx];
}

#define S1 (IND * HCV)
#define S2 (HCV * HCV)
#define S3 (HCV * OUTD)
#define STOT (S1 + S2 + S3)
#define XTOT (NN * IND)
__global__ void prep_kernel(const float* __restrict__ W1, const float* __restrict__ W2,
                            const float* __restrict__ W3, const float* __restrict__ x,
                            const float* __restrict__ as1, const float* __restrict__ ad1,
                            _Float16* __restrict__ T1, _Float16* __restrict__ T2,
                            _Float16* __restrict__ T3, _Float16* __restrict__ xh,
                            float* __restrict__ w1p, int* __restrict__ cnt) {
    int idx = blockIdx.x * blockDim.x + threadIdx.x;
    if (idx < S1) cvt_one(W1, T1, idx, IND, HCV);
    else if (idx < S1 + S2) cvt_one(W2, T2, idx - S1, HCV, HCV);
    else if (idx < STOT) cvt_one(W3, T3, idx - S1 - S2, HCV, OUTD);
    else if (idx < STOT + NN) cnt[idx - STOT] = 0;
    else if (idx < STOT + NN + XTOT) {
        int j = idx - STOT - NN;
        xh[j] = (_Float16)x[j];
    } else if (idx < STOT + NN + XTOT + IND * 16) {
        int j = idx - STOT - NN - XTOT;
        int c = j >> 4, o = j & 15;
        int hh = o & 7;
        const float* av = (o < 8) ? as1 : ad1;
        float s = 0.f;
        #pragma unroll 8
        for (int jj = 0; jj < HID; jj++)
            s = fmaf(W1[c * HCV + hh * HID + jj], av[hh * HID + jj], s);
        w1p[c * 16 + o] = s;
    }
}

// ---------------- CSR build ----------------

__global__ void count_kernel(const int* __restrict__ ei, int* __restrict__ cnt) {
    int i = blockIdx.x * blockDim.x + threadIdx.x;
    if (i >= ETOT) return;
    int v = (i < EE) ? ei[EE + i] : (i - EE);
    atomicAdd(&cnt[v], 1);
}

#define SCH 20
__global__ __launch_bounds__(1024) void scan_kernel(const int* __restrict__ cnt,
                                                    int* __restrict__ row_ptr,
                                                    int* __restrict__ cursor) {
    __shared__ int wtot[16];
    __shared__ int woff[16];
    int t = threadIdx.x;
    int lane = t & 63;
    int wid = t >> 6;
    int base = t * SCH;
    int vals[SCH];
    int s = 0;
    #pragma unroll
    for (int i = 0; i < SCH; i++) {
        int idx = base + i;
        int v = (idx < NN) ? cnt[idx] : 0;
        vals[i] = v;
        s += v;
    }
    int incl = s;
    #pragma unroll
    for (int off = 1; off < 64; off <<= 1) {
        int u = __shfl_up(incl, off);
        if (lane >= off) incl += u;
    }
    int excl = incl - s;
    if (lane == 63) wtot[wid] = incl;
    __syncthreads();
    if (t == 0) {
        int run = 0;
        #pragma unroll
        for (int j = 0; j < 16; j++) { woff[j] = run; run += wtot[j]; }
        row_ptr[NN] = run;
    }
    __syncthreads();
    int run = woff[wid] + excl;
    #pragma unroll
    for (int i = 0; i < SCH; i++) {
        int idx = base + i;
        if (idx < NN) { row_ptr[idx] = run; cursor[idx] = run; run += vals[i]; }
    }
}

__global__ void fill_kernel(const int* __restrict__ ei, int* __restrict__ cursor,
                            int* __restrict__ csr_src) {
    int i = blockIdx.x * blockDim.x + threadIdx.x;
    if (i >= ETOT) return;
    int u, v;
    if (i < EE) { u = ei[i]; v = ei[EE + i]; }
    else        { u = i - EE; v = i - EE; }
    int pos = atomicAdd(&cursor[v], 1);
    csr_src[pos] = u;
}

// ---------------- layer-1 half-logits from x (thin dot) ----------------
__global__ void al1_thin(const float* __restrict__ x, const float* __restrict__ w1p,
                         float* __restrict__ als, float* __restrict__ ald) {
    int gid = blockIdx.x * blockDim.x + threadIdx.x;
    int node = gid >> 4, o = gid & 15;
    if (node >= NN) return;
    const float* xr = x + (size_t)node * IND;
    float s = 0.f;
    #pragma unroll 4
    for (int c = 0; c < IND; c++)
        s = fmaf(xr[c], w1p[c * 16 + o], s);
    if (o < 8) als[node * 8 + o] = s;
    else       ald[node * 8 + (o - 8)] = s;
}

// ---------------- layer-1 gather: wave per node, per-head agg of x, unroll 4 ----------------
__global__ __launch_bounds__(256) void gather1_kernel(const _Float16* __restrict__ xh,
                                                      const int* __restrict__ row_ptr,
                                                      const int* __restrict__ csr_src,
                                                      const float* __restrict__ als,
                                                      const float* __restrict__ ald,
                                                      _Float16* __restrict__ xagg) {
    int lane = threadIdx.x & 63;
    int v = blockIdx.x * 4 + (threadIdx.x >> 6);
    if (v >= NN) return;
    int hd = lane >> 3;
    int cg = lane & 7;
    float adst = ald[v * NHEADS + hd];
    int s0 = row_ptr[v], s1 = row_ptr[v + 1];
    float acc[16] = {};
    float l = 0.f;
    int i = s0;
    for (; i + 4 <= s1; i += 4) {
        int u[4]; float p[4];
        #pragma unroll
        for (int e = 0; e < 4; e++) u[e] = csr_src[i + e];
        #pragma unroll
        for (int e = 0; e < 4; e++) {
            float t = als[u[e] * NHEADS + hd] + adst;
            t = (t > 0.f) ? t : NEG_SLOPE * t;
            p[e] = __expf(fminf(t, 80.f));
        }
        half8 a[4], b[4];
        #pragma unroll
        for (int e = 0; e < 4; e++) {
            a[e] = *(const half8*)&xh[(size_t)u[e] * IND + cg * 16];
            b[e] = *(const half8*)&xh[(size_t)u[e] * IND + cg * 16 + 8];
        }
        #pragma unroll
        for (int e = 0; e < 4; e++) {
            l += p[e];
            #pragma unroll
            for (int j = 0; j < 8; j++) {
                acc[j]     = fmaf(p[e], (float)a[e][j], acc[j]);
                acc[j + 8] = fmaf(p[e], (float)b[e][j], acc[j + 8]);
            }
        }
    }
    for (; i < s1; i++) {
        int u0 = csr_src[i];
        float t0 = als[u0 * NHEADS + hd] + adst;
        t0 = (t0 > 0.f) ? t0 : NEG_SLOPE * t0;
        float p0 = __expf(fminf(t0, 80.f));
        half8 a0 = *(const half8*)&xh[(size_t)u0 * IND + cg * 16];
        half8 b0 = *(const half8*)&xh[(size_t)u0 * IND + cg * 16 + 8];
        l += p0;
        #pragma unroll
        for (int j = 0; j < 8; j++) {
            acc[j]     = fmaf(p0, (float)a0[j], acc[j]);
            acc[j + 8] = fmaf(p0, (float)b0[j], acc[j + 8]);
        }
    }
    float inv = 1.f / (l + 1e-16f);
    half8 o0, o1;
    #pragma unroll
    for (int j = 0; j < 8; j++) {
        o0[j] = (_Float16)(acc[j] * inv);
        o1[j] = (_Float16)(acc[j + 8] * inv);
    }
    size_t base = (size_t)v * (NHEADS * IND) + hd * IND + cg * 16;
    *(half8*)&xagg[base] = o0;
    *(half8*)&xagg[base + 8] = o1;
}

// ---------------- block-diagonal GEMM (layer 1) ----------------
#define LDK 40
__global__ __launch_bounds__(256) void gemm1_bd(const _Float16* __restrict__ xagg,
                                                const _Float16* __restrict__ Bt,
                                                const float* __restrict__ bias,
                                                _Float16* __restrict__ gact,
                                                int M) {
    __shared__ _Float16 sA[64 * LDK];
    __shared__ _Float16 sB[64 * LDK];
    int tid = threadIdx.x;
    int lane = tid & 63;
    int wv = tid >> 6;
    int m0 = blockIdx.x * 64;
    int h = blockIdx.y;
    int quad = lane >> 4;
    int l15 = lane & 15;
    int arow = tid >> 2;
    int ac4 = tid & 3;

    floatx4 acc[4] = {};

    for (int k0 = 0; k0 < IND; k0 += 32) {
        {
            int gm = m0 + arow;
            int4 va;
            if (gm < M) va = *(const int4*)&xagg[(size_t)gm * (NHEADS * IND) + h * IND + k0 + ac4 * 8];
            else        va = make_int4(0, 0, 0, 0);
            *(int4*)&sA[arow * LDK + ac4 * 8] = va;
            int gn = h * 64 + arow;
            int4 vb = *(const int4*)&Bt[(size_t)gn * IND + k0 + ac4 * 8];
            *(int4*)&sB[arow * LDK + ac4 * 8] = vb;
        }
        __syncthreads();
        half8 a[4], b;
        #pragma unroll
        for (int i = 0; i < 4; i++)
            a[i] = *(const half8*)&sA[(i * 16 + l15) * LDK + quad * 8];
        b = *(const half8*)&sB[(wv * 16 + l15) * LDK + quad * 8];
        #pragma unroll
        for (int i = 0; i < 4; i++)
            acc[i] = __builtin_amdgcn_mfma_f32_16x16x32_f16(a[i], b, acc[i], 0, 0, 0);
        __syncthreads();
    }
    #pragma unroll
    for (int i = 0; i < 4; i++) {
        #pragma unroll
        for (int r = 0; r < 4; r++) {
            int gm = m0 + i * 16 + quad * 4 + r;
            if (gm < M) {
                int col = h * 64 + wv * 16 + l15;
                float o = acc[i][r] + bias[col];
                o = (o > 0.f) ? o : (__expf(o) - 1.f);
                gact[(size_t)gm * HCV + col] = (_Float16)o;
            }
        }
    }
}

// ---------------- MFMA GEMM 64x128 (layer 2): f16, fused al epilogue (HEAD-MAJOR als2/ald2) ----------------
__global__ __launch_bounds__(256) void gemm_l2(const _Float16* __restrict__ A,
                                               const _Float16* __restrict__ Bt,
                                               _Float16* __restrict__ C16,
                                               const float* __restrict__ a_src,
                                               const float* __restrict__ a_dst,
                                               float* __restrict__ als2,
                                               float* __restrict__ ald2,
                                               int M, int K) {
    __shared__ _Float16 sA[64 * LDK];
    __shared__ _Float16 sB[128 * LDK];
    __shared__ float psum_s[4][64];
    __shared__ float psum_d[4][64];
    int tid = threadIdx.x;
    int lane = tid & 63;
    int wv = tid >> 6;
    int m0 = blockIdx.x * 64, n0 = blockIdx.y * 128;
    int quad = lane >> 4;
    int l15 = lane & 15;
    int arow = tid >> 2;
    int ac4 = tid & 3;

    floatx4 acc[4][2] = {};

    for (int k0 = 0; k0 < K; k0 += 32) {
        {
            int gm = m0 + arow;
            int4 va;
            if (gm < M) va = *(const int4*)&A[(size_t)gm * K + k0 + ac4 * 8];
            else        va = make_int4(0, 0, 0, 0);
            *(int4*)&sA[arow * LDK + ac4 * 8] = va;
            #pragma unroll
            for (int r = 0; r < 2; r++) {
                int gn = n0 + arow + r * 64;
                int4 vb = *(const int4*)&Bt[(size_t)gn * K + k0 + ac4 * 8];
                *(int4*)&sB[(arow + r * 64) * LDK + ac4 * 8] = vb;
            }
        }
        __syncthreads();
        half8 a[4], b[2];
        #pragma unroll
        for (int i = 0; i < 4; i++)
            a[i] = *(const half8*)&sA[(i * 16 + l15) * LDK + quad * 8];
        #pragma unroll
        for (int j = 0; j < 2; j++)
            b[j] = *(const half8*)&sB[(wv * 32 + j * 16 + l15) * LDK + quad * 8];
        #pragma unroll
        for (int i = 0; i < 4; i++)
            #pragma unroll
            for (int j = 0; j < 2; j++)
                acc[i][j] = __builtin_amdgcn_mfma_f32_16x16x32_f16(a[i], b[j], acc[i][j], 0, 0, 0);
        __syncthreads();
    }
    #pragma unroll
    for (int i = 0; i < 4; i++) {
        #pragma unroll
        for (int r = 0; r < 4; r++) {
            int gm = m0 + i * 16 + quad * 4 + r;
            if (gm < M) {
                #pragma unroll
                for (int j = 0; j < 2; j++)
                    C16[(size_t)gm * HCV + n0 + wv * 32 + j * 16 + l15] = (_Float16)acc[i][j][r];
            }
        }
    }
    int h0 = n0 >> 6;
    float as_v[2], ad_v[2];
    #pragma unroll
    for (int j = 0; j < 2; j++) {
        int dim = (wv * 32 + j * 16 + l15) & 63;
        int hh = h0 + (wv >> 1);
        as_v[j] = a_src[hh * HID + dim];
        ad_v[j] = a_dst[hh * HID + dim];
    }
    #pragma unroll
    for (int i = 0; i < 4; i++) {
        #pragma unroll
        for (int r = 0; r < 4; r++) {
            float ps = acc[i][0][r] * as_v[0] + acc[i][1][r] * as_v[1];
            float pd = acc[i][0][r] * ad_v[0] + acc[i][1][r] * ad_v[1];
            #pragma unroll
            for (int off = 1; off <= 8; off <<= 1) {
                ps += __shfl_xor(ps, off);
                pd += __shfl_xor(pd, off);
            }
            if (l15 == 0) {
                int row = i * 16 + quad * 4 + r;
                psum_s[wv][row] = ps;
                psum_d[wv][row] = pd;
            }
        }
    }
    __syncthreads();
    if (tid < 64) {
        int gm = m0 + tid;
        if (gm < M) {
            // head-major: als2[h][node] so each XCD's gather2 pass touches an 80KB slice
            als2[(size_t)h0 * NN + gm]       = psum_s[0][tid] + psum_s[1][tid];
            als2[(size_t)(h0 + 1) * NN + gm] = psum_s[2][tid] + psum_s[3][tid];
            ald2[(size_t)h0 * NN + gm]       = psum_d[0][tid] + psum_d[1][tid];
            ald2[(size_t)(h0 + 1) * NN + gm] = psum_d[2][tid] + psum_d[3][tid];
        }
    }
}

// ---------------- MFMA GEMM 64x128 (layer 3): f16 C out, fused al3 ----------------
__global__ __launch_bounds__(256) void gemm3(const _Float16* __restrict__ A,
                                             const _Float16* __restrict__ Bt,
                                             _Float16* __restrict__ C16,
                                             const float* __restrict__ a_src,
                                             const float* __restrict__ a_dst,
                                             float* __restrict__ als,
                                             float* __restrict__ ald,
                                             int M, int K) {
    __shared__ _Float16 sA[64 * LDK];
    __shared__ _Float16 sB[128 * LDK];
    __shared__ float psum_s[4][64];
    __shared__ float psum_d[4][64];
    int tid = threadIdx.x;
    int lane = tid & 63;
    int wv = tid >> 6;
    int m0 = blockIdx.x * 64;
    int quad = lane >> 4;
    int l15 = lane & 15;
    int arow = tid >> 2;
    int ac4 = tid & 3;

    floatx4 acc[4][2] = {};

    for (int k0 = 0; k0 < K; k0 += 32) {
        {
            int gm = m0 + arow;
            int4 va;
            if (gm < M) va = *(const int4*)&A[(size_t)gm * K + k0 + ac4 * 8];
            else        va = make_int4(0, 0, 0, 0);
            *(int4*)&sA[arow * LDK + ac4 * 8] = va;
            #pragma unroll
            for (int r = 0; r < 2; r++) {
                int gn = arow + r * 64;
                int4 vb = *(const int4*)&Bt[(size_t)gn * K + k0 + ac4 * 8];
                *(int4*)&sB[(arow + r * 64) * LDK + ac4 * 8] = vb;
            }
        }
        __syncthreads();
        half8 a[4], b[2];
        #pragma unroll
        for (int i = 0; i < 4; i++)
            a[i] = *(const half8*)&sA[(i * 16 + l15) * LDK + quad * 8];
        #pragma unroll
        for (int j = 0; j < 2; j++)
            b[j] = *(const half8*)&sB[(wv * 32 + j * 16 + l15) * LDK + quad * 8];
        #pragma unroll
        for (int i = 0; i < 4; i++)
            #pragma unroll
            for (int j = 0; j < 2; j++)
                acc[i][j] = __builtin_amdgcn_mfma_f32_16x16x32_f16(a[i], b[j], acc[i][j], 0, 0, 0);
        __syncthreads();
    }
    #pragma unroll
    for (int i = 0; i < 4; i++) {
        #pragma unroll
        for (int r = 0; r < 4; r++) {
            int gm = m0 + i * 16 + quad * 4 + r;
            if (gm < M) {
                #pragma unroll
                for (int j = 0; j < 2; j++)
                    C16[(size_t)gm * OUTD + wv * 32 + j * 16 + l15] = (_Float16)acc[i][j][r];
            }
        }
    }
    float as_v[2], ad_v[2];
    #pragma unroll
    for (int j = 0; j < 2; j++) {
        as_v[j] = a_src[wv * 32 + j * 16 + l15];
        ad_v[j] = a_dst[wv * 32 + j * 16 + l15];
    }
    #pragma unroll
    for (int i = 0; i < 4; i++) {
        #pragma unroll
        for (int r = 0; r < 4; r++) {
            float ps = acc[i][0][r] * as_v[0] + acc[i][1][r] * as_v[1];
            float pd = acc[i][0][r] * ad_v[0] + acc[i][1][r] * ad_v[1];
            #pragma unroll
            for (int off = 1; off <= 8; off <<= 1) {
                ps += __shfl_xor(ps, off);
                pd += __shfl_xor(pd, off);
            }
            if (l15 == 0) {
                int row = i * 16 + quad * 4 + r;
                psum_s[wv][row] = ps;
                psum_d[wv][row] = pd;
            }
        }
    }
    __syncthreads();
    if (tid < 64) {
        int gm = m0 + tid;
        if (gm < M) {
            als[gm] = psum_s[0][tid] + psum_s[1][tid] + psum_s[2][tid] + psum_s[3][tid];
            ald[gm] = psum_d[0][tid] + psum_d[1][tid] + psum_d[2][tid] + psum_d[3][tid];
        }
    }
}

// ---------------- layer-2 gather: wave = (1 head, 8 nodes), 8 lanes per node ----------------
// head = blockIdx.x & 7 keeps the per-XCD working set at one head slice (2.56 MB h + 80 KB
// als2) -> L2-resident. Each 8-lane subgroup OWNS one node: walks its edge list serially,
// loads the 128B head-slice per edge as half8 (16B/lane, coalesced), accumulates the node's
// 64 dims in-register (acc[8]/lane). No cross-lane reduction: l is replicated within the
// subgroup, each lane stores its own half8. Divergence cost = max degree of 8 nodes (~1.3x).
__global__ __launch_bounds__(256) void gather2_kernel(const _Float16* __restrict__ h,
                                                      const int* __restrict__ row_ptr,
                                                      const int* __restrict__ csr_src,
                                                      const float* __restrict__ als2,
                                                      const float* __restrict__ ald2,
                                                      const float* __restrict__ bias,
                                                      _Float16* __restrict__ gout) {
    int tid = threadIdx.x;
    int lane = tid & 63;
    int wid = tid >> 6;
    int bid = blockIdx.x;
    int hd = bid & 7;                    // head == XCD (round-robin)
    int sub = lane >> 3;                 // node slot 0..7
    int dl = lane & 7;                   // dim octet within the head
    int v = (bid >> 3) * 32 + wid * 8 + sub;
    if (v >= NN) return;
    const float* asl = als2 + (size_t)hd * NN;
    float adst = ald2[(size_t)hd * NN + v];
    int s0 = row_ptr[v], s1 = row_ptr[v + 1];
    const _Float16* hh = h + hd * HID + dl * 8;
    float acc[8] = {};
    float l = 0.f;
    int j = s0;
    for (; j + 2 <= s1; j += 2) {
        int u0 = csr_src[j];
        int u1 = csr_src[j + 1];
        half8 x0 = *(const half8*)&hh[(size_t)u0 * HCV];
        half8 x1 = *(const half8*)&hh[(size_t)u1 * HCV];
        float t0 = asl[u0] + adst;
        float t1 = asl[u1] + adst;
        t0 = (t0 > 0.f) ? t0 : NEG_SLOPE * t0;
        t1 = (t1 > 0.f) ? t1 : NEG_SLOPE * t1;
        float p0 = __expf(fminf(t0, 80.f));
        float p1 = __expf(fminf(t1, 80.f));
        l += p0 + p1;
        #pragma unroll
        for (int k = 0; k < 8; k++) {
            acc[k] = fmaf(p0, (float)x0[k], acc[k]);
            acc[k] = fmaf(p1, (float)x1[k], acc[k]);
        }
    }
    if (j < s1) {
        int u0 = csr_src[j];
        half8 x0 = *(const half8*)&hh[(size_t)u0 * HCV];
        float t0 = asl[u0] + adst;
        t0 = (t0 > 0.f) ? t0 : NEG_SLOPE * t0;
        float p0 = __expf(fminf(t0, 80.f));
        l += p0;
        #pragma unroll
        for (int k = 0; k < 8; k++)
            acc[k] = fmaf(p0, (float)x0[k], acc[k]);
    }
    float inv = 1.f / (l + 1e-16f);
    half8 hv;
    #pragma unroll
    for (int k = 0; k < 8; k++) {
        float o = fmaf(acc[k], inv, bias[hd * HID + dl * 8 + k]);
        o = (o > 0.f) ? o : (__expf(o) - 1.f);   // ELU
        hv[k] = (_Float16)o;
    }
    half8* dst = (half8*)&gout[(size_t)v * HCV + hd * HID + dl * 8];
    __builtin_nontemporal_store(hv, dst);
}

// ---------------- layer-3 gather (fp16 h3 -> fp32 out, with max pass) ----------------
__global__ __launch_bounds__(256) void gather3_kernel(const _Float16* __restrict__ h,
                                                      const int* __restrict__ row_ptr,
                                                      const int* __restrict__ csr_src,
                                                      const float* __restrict__ als,
                                                      const float* __restrict__ ald,
                                                      const float* __restrict__ bias,
                                                      float* __restrict__ out) {
    int lane = threadIdx.x & 63;
    int v = blockIdx.x * 4 + (threadIdx.x >> 6);
    if (v >= NN) return;
    int e_sub = lane >> 4;
    int cg = lane & 15;
    float adst = ald[v];
    int s0 = row_ptr[v], s1 = row_ptr[v + 1];
    float m = -INFINITY;
    for (int i = s0 + e_sub; i < s1; i += 4) {
        int u = csr_src[i];
        float t = als[u] + adst;
        t = (t > 0.f) ? t : NEG_SLOPE * t;
        m = fmaxf(m, t);
    }
    m = fmaxf(m, __shfl_xor(m, 16));
    m = fmaxf(m, __shfl_xor(m, 32));
    float acc[8] = {};
    float l = 0.f;
    for (int i = s0 + e_sub; i < s1; i += 4) {
        int u = csr_src[i];
        float t = als[u] + adst;
        t = (t > 0.f) ? t : NEG_SLOPE * t;
        float p = __expf(t - m);
        half8 x = *(const half8*)&h[(size_t)u * OUTD + cg * 8];
        l += p;
        #pragma unroll
        for (int j = 0; j < 8; j++)
            acc[j] = fmaf(p, (float)x[j], acc[j]);
    }
    l += __shfl_xor(l, 16);
    l += __shfl_xor(l, 32);
    #pragma unroll
    for (int j = 0; j < 8; j++) {
        acc[j] += __shfl_xor(acc[j], 16);
        acc[j] += __shfl_xor(acc[j], 32);
    }
    if (e_sub == 0) {
        float inv = 1.f / (l + 1e-16f);
        float4 o0, o1;
        o0.x = fmaf(acc[0], inv, bias[cg * 8 + 0]);
        o0.y = fmaf(acc[1], inv, bias[cg * 8 + 1]);
        o0.z = fmaf(acc[2], inv, bias[cg * 8 + 2]);
        o0.w = fmaf(acc[3], inv, bias[cg * 8 + 3]);
        o1.x = fmaf(acc[4], inv, bias[cg * 8 + 4]);
        o1.y = fmaf(acc[5], inv, bias[cg * 8 + 5]);
        o1.z = fmaf(acc[6], inv, bias[cg * 8 + 6]);
        o1.w = fmaf(acc[7], inv, bias[cg * 8 + 7]);
        *(float4*)&out[(size_t)v * OUTD + cg * 8] = o0;
        *(float4*)&out[(size_t)v * OUTD + cg * 8 + 4] = o1;
    }
}

// ---------------- launch ----------------

extern "C" void kernel_launch(void* const* d_in, const int* in_sizes, int n_in,
                              void* d_out, int out_size, void* d_ws, size_t ws_size,
                              hipStream_t stream) {
    const float* x     = (const float*)d_in[0];
    const int*   ei    = (const int*)d_in[1];
    const float* W1    = (const float*)d_in[2];
    const float* as1   = (const float*)d_in[3];
    const float* ad1   = (const float*)d_in[4];
    const float* b1    = (const float*)d_in[5];
    const float* W2    = (const float*)d_in[6];
    const float* as2   = (const float*)d_in[7];
    const float* ad2   = (const float*)d_in[8];
    const float* b2    = (const float*)d_in[9];
    const float* W3    = (const float*)d_in[10];
    const float* as3   = (const float*)d_in[11];
    const float* ad3   = (const float*)d_in[12];
    const float* b3    = (const float*)d_in[13];
    float* out = (float*)d_out;

    size_t off = 0;
    auto carve = [&](size_t bytes) {
        void* p = (char*)d_ws + off;
        off += (bytes + 255) & ~(size_t)255;
        return p;
    };
    int* row_ptr   = (int*)carve((NN + 1) * sizeof(int));
    int* cursor    = (int*)carve(NN * sizeof(int));
    int* csr_src   = (int*)carve(ETOT * sizeof(int));
    _Float16* xh   = (_Float16*)carve((size_t)NN * IND * sizeof(_Float16));
    _Float16* xagg = (_Float16*)carve((size_t)NN * NHEADS * IND * sizeof(_Float16));
    _Float16* gact = (_Float16*)carve((size_t)NN * HCV * sizeof(_Float16));
    _Float16* hf16 = (_Float16*)carve((size_t)NN * HCV * sizeof(_Float16));
    _Float16* h3   = (_Float16*)carve((size_t)NN * OUTD * sizeof(_Float16));
    float* als     = (float*)carve((size_t)NN * NHEADS * sizeof(float));
    float* ald     = (float*)carve((size_t)NN * NHEADS * sizeof(float));
    float* als2    = (float*)carve((size_t)NN * NHEADS * sizeof(float));
    float* ald2    = (float*)carve((size_t)NN * NHEADS * sizeof(float));
    float* w1p     = (float*)carve((size_t)IND * 16 * sizeof(float));
    _Float16* W1T  = (_Float16*)carve((size_t)S1 * sizeof(_Float16));
    _Float16* W2T  = (_Float16*)carve((size_t)S2 * sizeof(_Float16));
    _Float16* W3T  = (_Float16*)carve((size_t)S3 * sizeof(_Float16));
    _Float16* gact2 = xagg;   // aliases xagg (dead after gemm1_bd)
    (void)ws_size; (void)n_in; (void)in_sizes; (void)out_size;

    dim3 blk(256);

    // ---- prep ----
    int prep_n = STOT + NN + XTOT + IND * 16;
    prep_kernel<<<(prep_n + 255) / 256, blk, 0, stream>>>(W1, W2, W3, x, as1, ad1,
        W1T, W2T, W3T, xh, w1p, cursor);

    // ---- CSR build ----
    count_kernel<<<(ETOT + 255) / 256, blk, 0, stream>>>(ei, cursor);
    scan_kernel<<<1, 1024, 0, stream>>>(cursor, row_ptr, cursor);
    fill_kernel<<<(ETOT + 255) / 256, blk, 0, stream>>>(ei, cursor, csr_src);

    int mt64 = (NN + 63) / 64;
    int nwaves_n = (NN + 3) / 4;

    // ---- layer 1: input-side aggregation (wave per node) ----
    al1_thin<<<(NN * 16 + 255) / 256, blk, 0, stream>>>(x, w1p, als, ald);
    gather1_kernel<<<nwaves_n, blk, 0, stream>>>(xh, row_ptr, csr_src, als, ald, xagg);
    gemm1_bd<<<dim3(mt64, NHEADS), blk, 0, stream>>>(xagg, W1T, b1, gact, NN);

    // ---- layer 2: output-side (wave = (head, 8 nodes), head==XCD) ----
    gemm_l2<<<dim3(mt64, HCV / 128), blk, 0, stream>>>(gact, W2T, hf16, as2, ad2, als2, ald2, NN, HCV);
    int nb2 = (NN + 31) / 32;   // node-blocks per head (4 waves x 8 nodes per block)
    gather2_kernel<<<dim3(nb2 * 8), blk, 0, stream>>>(hf16, row_ptr, csr_src, als2, ald2, b2, gact2);

    // ---- layer 3: output-side, fp16 h3 ----
    gemm3<<<dim3(mt64, 1), blk, 0, stream>>>(gact2, W3T, h3, as3, ad3, als, ald, NN, HCV);
    gather3_kernel<<<nwaves_n, blk, 0, stream>>>(h3, row_ptr, csr_src, als, ald, b3, out);
}

// Round 4
// 314.438 us; speedup vs baseline: 1.2206x; 1.0564x over previous
//
#include <hip/hip_runtime.h>
#include <math.h>

#define NN 20000
#define EE 320000
#define ETOT 340000   // EE + NN self-loops
#define NHEADS 8
#define HID 64
#define HCV 512       // NHEADS*HID
#define IND 128
#define OUTD 128
#define NEG_SLOPE 0.2f

typedef __attribute__((ext_vector_type(8))) _Float16 half8;
typedef __attribute__((ext_vector_type(4))) float floatx4;

// ---------------- prep: W cvt + x cvt + zero cnt ----------------
__device__ __forceinline__ void cvt_one(const float* W, _Float16* T, int idx, int K, int N) {
    int k = idx / N, n = idx - k * N;
    T[(size_t)n * K + k] = (_Float16)W[idx];
}

#define S1 (IND * HCV)
#define S2 (HCV * HCV)
#define S3 (HCV * OUTD)
#define STOT (S1 + S2 + S3)
#define XTOT (NN * IND)
__global__ void prep_kernel(const float* __restrict__ W1, const float* __restrict__ W2,
                            const float* __restrict__ W3, const float* __restrict__ x,
                            _Float16* __restrict__ T1, _Float16* __restrict__ T2,
                            _Float16* __restrict__ T3, _Float16* __restrict__ xh,
                            int* __restrict__ cnt) {
    int idx = blockIdx.x * blockDim.x + threadIdx.x;
    if (idx < S1) cvt_one(W1, T1, idx, IND, HCV);
    else if (idx < S1 + S2) cvt_one(W2, T2, idx - S1, HCV, HCV);
    else if (idx < STOT) cvt_one(W3, T3, idx - S1 - S2, HCV, OUTD);
    else if (idx < STOT + NN) cnt[idx - STOT] = 0;
    else if (idx < STOT + NN + XTOT) {
        int j = idx - STOT - NN;
        xh[j] = (_Float16)x[j];
    }
}

// ---------------- CSR build ----------------

__global__ void count_kernel(const int* __restrict__ ei, int* __restrict__ cnt) {
    int i = blockIdx.x * blockDim.x + threadIdx.x;
    if (i >= ETOT) return;
    int v = (i < EE) ? ei[EE + i] : (i - EE);
    atomicAdd(&cnt[v], 1);
}

#define SCH 20
__global__ __launch_bounds__(1024) void scan_kernel(const int* __restrict__ cnt,
                                                    int* __restrict__ row_ptr,
                                                    int* __restrict__ cursor) {
    __shared__ int wtot[16];
    __shared__ int woff[16];
    int t = threadIdx.x;
    int lane = t & 63;
    int wid = t >> 6;
    int base = t * SCH;
    int vals[SCH];
    int s = 0;
    #pragma unroll
    for (int i = 0; i < SCH; i++) {
        int idx = base + i;
        int v = (idx < NN) ? cnt[idx] : 0;
        vals[i] = v;
        s += v;
    }
    int incl = s;
    #pragma unroll
    for (int off = 1; off < 64; off <<= 1) {
        int u = __shfl_up(incl, off);
        if (lane >= off) incl += u;
    }
    int excl = incl - s;
    if (lane == 63) wtot[wid] = incl;
    __syncthreads();
    if (t == 0) {
        int run = 0;
        #pragma unroll
        for (int j = 0; j < 16; j++) { woff[j] = run; run += wtot[j]; }
        row_ptr[NN] = run;
    }
    __syncthreads();
    int run = woff[wid] + excl;
    #pragma unroll
    for (int i = 0; i < SCH; i++) {
        int idx = base + i;
        if (idx < NN) { row_ptr[idx] = run; cursor[idx] = run; run += vals[i]; }
    }
}

__global__ void fill_kernel(const int* __restrict__ ei, int* __restrict__ cursor,
                            int* __restrict__ csr_src) {
    int i = blockIdx.x * blockDim.x + threadIdx.x;
    if (i >= ETOT) return;
    int u, v;
    if (i < EE) { u = ei[i]; v = ei[EE + i]; }
    else        { u = i - EE; v = i - EE; }
    int pos = atomicAdd(&cursor[v], 1);
    csr_src[pos] = u;
}

// ---------------- MFMA GEMM 64x128 (layers 1 & 2): f16, fused al epilogue (HEAD-MAJOR als/ald) ----------------
#define LDK 40
__global__ __launch_bounds__(256) void gemm_al(const _Float16* __restrict__ A,
                                               const _Float16* __restrict__ Bt,
                                               _Float16* __restrict__ C16,
                                               const float* __restrict__ a_src,
                                               const float* __restrict__ a_dst,
                                               float* __restrict__ als2,
                                               float* __restrict__ ald2,
                                               int M, int K) {
    __shared__ _Float16 sA[64 * LDK];
    __shared__ _Float16 sB[128 * LDK];
    __shared__ float psum_s[4][64];
    __shared__ float psum_d[4][64];
    int tid = threadIdx.x;
    int lane = tid & 63;
    int wv = tid >> 6;
    int m0 = blockIdx.x * 64, n0 = blockIdx.y * 128;
    int quad = lane >> 4;
    int l15 = lane & 15;
    int arow = tid >> 2;
    int ac4 = tid & 3;

    floatx4 acc[4][2] = {};

    for (int k0 = 0; k0 < K; k0 += 32) {
        {
            int gm = m0 + arow;
            int4 va;
            if (gm < M) va = *(const int4*)&A[(size_t)gm * K + k0 + ac4 * 8];
            else        va = make_int4(0, 0, 0, 0);
            *(int4*)&sA[arow * LDK + ac4 * 8] = va;
            #pragma unroll
            for (int r = 0; r < 2; r++) {
                int gn = n0 + arow + r * 64;
                int4 vb = *(const int4*)&Bt[(size_t)gn * K + k0 + ac4 * 8];
                *(int4*)&sB[(arow + r * 64) * LDK + ac4 * 8] = vb;
            }
        }
        __syncthreads();
        half8 a[4], b[2];
        #pragma unroll
        for (int i = 0; i < 4; i++)
            a[i] = *(const half8*)&sA[(i * 16 + l15) * LDK + quad * 8];
        #pragma unroll
        for (int j = 0; j < 2; j++)
            b[j] = *(const half8*)&sB[(wv * 32 + j * 16 + l15) * LDK + quad * 8];
        #pragma unroll
        for (int i = 0; i < 4; i++)
            #pragma unroll
            for (int j = 0; j < 2; j++)
                acc[i][j] = __builtin_amdgcn_mfma_f32_16x16x32_f16(a[i], b[j], acc[i][j], 0, 0, 0);
        __syncthreads();
    }
    #pragma unroll
    for (int i = 0; i < 4; i++) {
        #pragma unroll
        for (int r = 0; r < 4; r++) {
            int gm = m0 + i * 16 + quad * 4 + r;
            if (gm < M) {
                #pragma unroll
                for (int j = 0; j < 2; j++)
                    C16[(size_t)gm * HCV + n0 + wv * 32 + j * 16 + l15] = (_Float16)acc[i][j][r];
            }
        }
    }
    int h0 = n0 >> 6;
    float as_v[2], ad_v[2];
    #pragma unroll
    for (int j = 0; j < 2; j++) {
        int dim = (wv * 32 + j * 16 + l15) & 63;
        int hh = h0 + (wv >> 1);
        as_v[j] = a_src[hh * HID + dim];
        ad_v[j] = a_dst[hh * HID + dim];
    }
    #pragma unroll
    for (int i = 0; i < 4; i++) {
        #pragma unroll
        for (int r = 0; r < 4; r++) {
            float ps = acc[i][0][r] * as_v[0] + acc[i][1][r] * as_v[1];
            float pd = acc[i][0][r] * ad_v[0] + acc[i][1][r] * ad_v[1];
            #pragma unroll
            for (int off = 1; off <= 8; off <<= 1) {
                ps += __shfl_xor(ps, off);
                pd += __shfl_xor(pd, off);
            }
            if (l15 == 0) {
                int row = i * 16 + quad * 4 + r;
                psum_s[wv][row] = ps;
                psum_d[wv][row] = pd;
            }
        }
    }
    __syncthreads();
    if (tid < 64) {
        int gm = m0 + tid;
        if (gm < M) {
            // head-major: als2[h][node] so each XCD's gather pass touches an 80KB slice
            als2[(size_t)h0 * NN + gm]       = psum_s[0][tid] + psum_s[1][tid];
            als2[(size_t)(h0 + 1) * NN + gm] = psum_s[2][tid] + psum_s[3][tid];
            ald2[(size_t)h0 * NN + gm]       = psum_d[0][tid] + psum_d[1][tid];
            ald2[(size_t)(h0 + 1) * NN + gm] = psum_d[2][tid] + psum_d[3][tid];
        }
    }
}

// ---------------- MFMA GEMM 64x128 (layer 3): f16 C out, fused al3 ----------------
__global__ __launch_bounds__(256) void gemm3(const _Float16* __restrict__ A,
                                             const _Float16* __restrict__ Bt,
                                             _Float16* __restrict__ C16,
                                             const float* __restrict__ a_src,
                                             const float* __restrict__ a_dst,
                                             float* __restrict__ als,
                                             float* __restrict__ ald,
                                             int M, int K) {
    __shared__ _Float16 sA[64 * LDK];
    __shared__ _Float16 sB[128 * LDK];
    __shared__ float psum_s[4][64];
    __shared__ float psum_d[4][64];
    int tid = threadIdx.x;
    int lane = tid & 63;
    int wv = tid >> 6;
    int m0 = blockIdx.x * 64;
    int quad = lane >> 4;
    int l15 = lane & 15;
    int arow = tid >> 2;
    int ac4 = tid & 3;

    floatx4 acc[4][2] = {};

    for (int k0 = 0; k0 < K; k0 += 32) {
        {
            int gm = m0 + arow;
            int4 va;
            if (gm < M) va = *(const int4*)&A[(size_t)gm * K + k0 + ac4 * 8];
            else        va = make_int4(0, 0, 0, 0);
            *(int4*)&sA[arow * LDK + ac4 * 8] = va;
            #pragma unroll
            for (int r = 0; r < 2; r++) {
                int gn = arow + r * 64;
                int4 vb = *(const int4*)&Bt[(size_t)gn * K + k0 + ac4 * 8];
                *(int4*)&sB[(arow + r * 64) * LDK + ac4 * 8] = vb;
            }
        }
        __syncthreads();
        half8 a[4], b[2];
        #pragma unroll
        for (int i = 0; i < 4; i++)
            a[i] = *(const half8*)&sA[(i * 16 + l15) * LDK + quad * 8];
        #pragma unroll
        for (int j = 0; j < 2; j++)
            b[j] = *(const half8*)&sB[(wv * 32 + j * 16 + l15) * LDK + quad * 8];
        #pragma unroll
        for (int i = 0; i < 4; i++)
            #pragma unroll
            for (int j = 0; j < 2; j++)
                acc[i][j] = __builtin_amdgcn_mfma_f32_16x16x32_f16(a[i], b[j], acc[i][j], 0, 0, 0);
        __syncthreads();
    }
    #pragma unroll
    for (int i = 0; i < 4; i++) {
        #pragma unroll
        for (int r = 0; r < 4; r++) {
            int gm = m0 + i * 16 + quad * 4 + r;
            if (gm < M) {
                #pragma unroll
                for (int j = 0; j < 2; j++)
                    C16[(size_t)gm * OUTD + wv * 32 + j * 16 + l15] = (_Float16)acc[i][j][r];
            }
        }
    }
    float as_v[2], ad_v[2];
    #pragma unroll
    for (int j = 0; j < 2; j++) {
        as_v[j] = a_src[wv * 32 + j * 16 + l15];
        ad_v[j] = a_dst[wv * 32 + j * 16 + l15];
    }
    #pragma unroll
    for (int i = 0; i < 4; i++) {
        #pragma unroll
        for (int r = 0; r < 4; r++) {
            float ps = acc[i][0][r] * as_v[0] + acc[i][1][r] * as_v[1];
            float pd = acc[i][0][r] * ad_v[0] + acc[i][1][r] * ad_v[1];
            #pragma unroll
            for (int off = 1; off <= 8; off <<= 1) {
                ps += __shfl_xor(ps, off);
                pd += __shfl_xor(pd, off);
            }
            if (l15 == 0) {
                int row = i * 16 + quad * 4 + r;
                psum_s[wv][row] = ps;
                psum_d[wv][row] = pd;
            }
        }
    }
    __syncthreads();
    if (tid < 64) {
        int gm = m0 + tid;
        if (gm < M) {
            als[gm] = psum_s[0][tid] + psum_s[1][tid] + psum_s[2][tid] + psum_s[3][tid];
            ald[gm] = psum_d[0][tid] + psum_d[1][tid] + psum_d[2][tid] + psum_d[3][tid];
        }
    }
}

// ---------------- gather (layers 1 & 2): wave = (1 head, 8 nodes), 8 lanes per node ----------------
// head = blockIdx.x & 7 keeps the per-XCD working set at one head slice (2.56 MB h + 80 KB
// als2) -> L2-resident. Each 8-lane subgroup OWNS one node: walks its edge list (4-edge
// unroll for MLP), loads the 128B head-slice per edge as half8 (16B/lane, coalesced),
// accumulates 64 dims in-register. No cross-lane reduction; epilogue = bias + ELU.
__global__ __launch_bounds__(256) void gather_kernel(const _Float16* __restrict__ h,
                                                     const int* __restrict__ row_ptr,
                                                     const int* __restrict__ csr_src,
                                                     const float* __restrict__ als2,
                                                     const float* __restrict__ ald2,
                                                     const float* __restrict__ bias,
                                                     _Float16* __restrict__ gout) {
    int tid = threadIdx.x;
    int lane = tid & 63;
    int wid = tid >> 6;
    int bid = blockIdx.x;
    int hd = bid & 7;                    // head == XCD (round-robin)
    int sub = lane >> 3;                 // node slot 0..7
    int dl = lane & 7;                   // dim octet within the head
    int v = (bid >> 3) * 32 + wid * 8 + sub;
    if (v >= NN) return;
    const float* asl = als2 + (size_t)hd * NN;
    float adst = ald2[(size_t)hd * NN + v];
    int s0 = row_ptr[v], s1 = row_ptr[v + 1];
    const _Float16* hh = h + hd * HID + dl * 8;
    float acc[8] = {};
    float l = 0.f;
    int j = s0;
    for (; j + 4 <= s1; j += 4) {
        int u[4]; float p[4]; half8 xv[4];
        #pragma unroll
        for (int e = 0; e < 4; e++) u[e] = csr_src[j + e];
        #pragma unroll
        for (int e = 0; e < 4; e++) xv[e] = *(const half8*)&hh[(size_t)u[e] * HCV];
        #pragma unroll
        for (int e = 0; e < 4; e++) {
            float t = asl[u[e]] + adst;
            t = (t > 0.f) ? t : NEG_SLOPE * t;
            p[e] = __expf(fminf(t, 80.f));
        }
        #pragma unroll
        for (int e = 0; e < 4; e++) {
            l += p[e];
            #pragma unroll
            for (int k = 0; k < 8; k++)
                acc[k] = fmaf(p[e], (float)xv[e][k], acc[k]);
        }
    }
    for (; j < s1; j++) {
        int u0 = csr_src[j];
        half8 x0 = *(const half8*)&hh[(size_t)u0 * HCV];
        float t0 = asl[u0] + adst;
        t0 = (t0 > 0.f) ? t0 : NEG_SLOPE * t0;
        float p0 = __expf(fminf(t0, 80.f));
        l += p0;
        #pragma unroll
        for (int k = 0; k < 8; k++)
            acc[k] = fmaf(p0, (float)x0[k], acc[k]);
    }
    float inv = 1.f / (l + 1e-16f);
    half8 hv;
    #pragma unroll
    for (int k = 0; k < 8; k++) {
        float o = fmaf(acc[k], inv, bias[hd * HID + dl * 8 + k]);
        o = (o > 0.f) ? o : (__expf(o) - 1.f);   // ELU
        hv[k] = (_Float16)o;
    }
    half8* dst = (half8*)&gout[(size_t)v * HCV + hd * HID + dl * 8];
    __builtin_nontemporal_store(hv, dst);
}

// ---------------- layer-3 gather (fp16 h3 -> fp32 out, with max pass) ----------------
__global__ __launch_bounds__(256) void gather3_kernel(const _Float16* __restrict__ h,
                                                      const int* __restrict__ row_ptr,
                                                      const int* __restrict__ csr_src,
                                                      const float* __restrict__ als,
                                                      const float* __restrict__ ald,
                                                      const float* __restrict__ bias,
                                                      float* __restrict__ out) {
    int lane = threadIdx.x & 63;
    int v = blockIdx.x * 4 + (threadIdx.x >> 6);
    if (v >= NN) return;
    int e_sub = lane >> 4;
    int cg = lane & 15;
    float adst = ald[v];
    int s0 = row_ptr[v], s1 = row_ptr[v + 1];
    float m = -INFINITY;
    for (int i = s0 + e_sub; i < s1; i += 4) {
        int u = csr_src[i];
        float t = als[u] + adst;
        t = (t > 0.f) ? t : NEG_SLOPE * t;
        m = fmaxf(m, t);
    }
    m = fmaxf(m, __shfl_xor(m, 16));
    m = fmaxf(m, __shfl_xor(m, 32));
    float acc[8] = {};
    float l = 0.f;
    for (int i = s0 + e_sub; i < s1; i += 4) {
        int u = csr_src[i];
        float t = als[u] + adst;
        t = (t > 0.f) ? t : NEG_SLOPE * t;
        float p = __expf(t - m);
        half8 x = *(const half8*)&h[(size_t)u * OUTD + cg * 8];
        l += p;
        #pragma unroll
        for (int j = 0; j < 8; j++)
            acc[j] = fmaf(p, (float)x[j], acc[j]);
    }
    l += __shfl_xor(l, 16);
    l += __shfl_xor(l, 32);
    #pragma unroll
    for (int j = 0; j < 8; j++) {
        acc[j] += __shfl_xor(acc[j], 16);
        acc[j] += __shfl_xor(acc[j], 32);
    }
    if (e_sub == 0) {
        float inv = 1.f / (l + 1e-16f);
        float4 o0, o1;
        o0.x = fmaf(acc[0], inv, bias[cg * 8 + 0]);
        o0.y = fmaf(acc[1], inv, bias[cg * 8 + 1]);
        o0.z = fmaf(acc[2], inv, bias[cg * 8 + 2]);
        o0.w = fmaf(acc[3], inv, bias[cg * 8 + 3]);
        o1.x = fmaf(acc[4], inv, bias[cg * 8 + 4]);
        o1.y = fmaf(acc[5], inv, bias[cg * 8 + 5]);
        o1.z = fmaf(acc[6], inv, bias[cg * 8 + 6]);
        o1.w = fmaf(acc[7], inv, bias[cg * 8 + 7]);
        *(float4*)&out[(size_t)v * OUTD + cg * 8] = o0;
        *(float4*)&out[(size_t)v * OUTD + cg * 8 + 4] = o1;
    }
}

// ---------------- launch ----------------

extern "C" void kernel_launch(void* const* d_in, const int* in_sizes, int n_in,
                              void* d_out, int out_size, void* d_ws, size_t ws_size,
                              hipStream_t stream) {
    const float* x     = (const float*)d_in[0];
    const int*   ei    = (const int*)d_in[1];
    const float* W1    = (const float*)d_in[2];
    const float* as1   = (const float*)d_in[3];
    const float* ad1   = (const float*)d_in[4];
    const float* b1    = (const float*)d_in[5];
    const float* W2    = (const float*)d_in[6];
    const float* as2   = (const float*)d_in[7];
    const float* ad2   = (const float*)d_in[8];
    const float* b2    = (const float*)d_in[9];
    const float* W3    = (const float*)d_in[10];
    const float* as3   = (const float*)d_in[11];
    const float* ad3   = (const float*)d_in[12];
    const float* b3    = (const float*)d_in[13];
    float* out = (float*)d_out;

    size_t off = 0;
    auto carve = [&](size_t bytes) {
        void* p = (char*)d_ws + off;
        off += (bytes + 255) & ~(size_t)255;
        return p;
    };
    int* row_ptr   = (int*)carve((NN + 1) * sizeof(int));
    int* cursor    = (int*)carve(NN * sizeof(int));
    int* csr_src   = (int*)carve(ETOT * sizeof(int));
    _Float16* xh   = (_Float16*)carve((size_t)NN * IND * sizeof(_Float16));
    _Float16* h1   = (_Float16*)carve((size_t)NN * HCV * sizeof(_Float16));
    _Float16* gact = (_Float16*)carve((size_t)NN * HCV * sizeof(_Float16));
    _Float16* hf16 = (_Float16*)carve((size_t)NN * HCV * sizeof(_Float16));
    _Float16* h3   = (_Float16*)carve((size_t)NN * OUTD * sizeof(_Float16));
    float* als     = (float*)carve((size_t)NN * NHEADS * sizeof(float));
    float* ald     = (float*)carve((size_t)NN * NHEADS * sizeof(float));
    _Float16* W1T  = (_Float16*)carve((size_t)S1 * sizeof(_Float16));
    _Float16* W2T  = (_Float16*)carve((size_t)S2 * sizeof(_Float16));
    _Float16* W3T  = (_Float16*)carve((size_t)S3 * sizeof(_Float16));
    _Float16* gact2 = h1;   // aliases h1 (dead after layer-1 gather)
    (void)ws_size; (void)n_in; (void)in_sizes; (void)out_size;

    dim3 blk(256);

    // ---- prep ----
    int prep_n = STOT + NN + XTOT;
    prep_kernel<<<(prep_n + 255) / 256, blk, 0, stream>>>(W1, W2, W3, x,
        W1T, W2T, W3T, xh, cursor);

    // ---- CSR build ----
    count_kernel<<<(ETOT + 255) / 256, blk, 0, stream>>>(ei, cursor);
    scan_kernel<<<1, 1024, 0, stream>>>(cursor, row_ptr, cursor);
    fill_kernel<<<(ETOT + 255) / 256, blk, 0, stream>>>(ei, cursor, csr_src);

    int mt64 = (NN + 63) / 64;
    int nwaves_n = (NN + 3) / 4;
    int nb = (NN + 31) / 32;   // node-blocks per head for gather (4 waves x 8 nodes)

    // ---- layer 1: project-first (dense GEMM + fused al), then head-sliced gather ----
    gemm_al<<<dim3(mt64, HCV / 128), blk, 0, stream>>>(xh, W1T, h1, as1, ad1, als, ald, NN, IND);
    gather_kernel<<<dim3(nb * 8), blk, 0, stream>>>(h1, row_ptr, csr_src, als, ald, b1, gact);

    // ---- layer 2: identical structure ----
    gemm_al<<<dim3(mt64, HCV / 128), blk, 0, stream>>>(gact, W2T, hf16, as2, ad2, als, ald, NN, HCV);
    gather_kernel<<<dim3(nb * 8), blk, 0, stream>>>(hf16, row_ptr, csr_src, als, ald, b2, gact2);

    // ---- layer 3: output-side, fp16 h3 ----
    gemm3<<<dim3(mt64, 1), blk, 0, stream>>>(gact2, W3T, h3, as3, ad3, als, ald, NN, HCV);
    gather3_kernel<<<nwaves_n, blk, 0, stream>>>(h3, row_ptr, csr_src, als, ald, b3, out);
}

// Round 5
// 312.484 us; speedup vs baseline: 1.2282x; 1.0063x over previous
//
#include <hip/hip_runtime.h>
#include <math.h>

#define NN 20000
#define EE 320000
#define ETOT 340000   // EE + NN self-loops
#define NHEADS 8
#define HID 64
#define HCV 512       // NHEADS*HID
#define IND 128
#define OUTD 128
#define NEG_SLOPE 0.2f

typedef __attribute__((ext_vector_type(8))) _Float16 half8;
typedef __attribute__((ext_vector_type(4))) float floatx4;

// ---------------- prep: W cvt + x cvt + zero cnt ----------------
__device__ __forceinline__ void cvt_one(const float* W, _Float16* T, int idx, int K, int N) {
    int k = idx / N, n = idx - k * N;
    T[(size_t)n * K + k] = (_Float16)W[idx];
}

#define S1 (IND * HCV)
#define S2 (HCV * HCV)
#define S3 (HCV * OUTD)
#define STOT (S1 + S2 + S3)
#define XTOT (NN * IND)
__global__ void prep_kernel(const float* __restrict__ W1, const float* __restrict__ W2,
                            const float* __restrict__ W3, const float* __restrict__ x,
                            _Float16* __restrict__ T1, _Float16* __restrict__ T2,
                            _Float16* __restrict__ T3, _Float16* __restrict__ xh,
                            int* __restrict__ cnt) {
    int idx = blockIdx.x * blockDim.x + threadIdx.x;
    if (idx < S1) cvt_one(W1, T1, idx, IND, HCV);
    else if (idx < S1 + S2) cvt_one(W2, T2, idx - S1, HCV, HCV);
    else if (idx < STOT) cvt_one(W3, T3, idx - S1 - S2, HCV, OUTD);
    else if (idx < STOT + NN) cnt[idx - STOT] = 0;
    else if (idx < STOT + NN + XTOT) {
        int j = idx - STOT - NN;
        xh[j] = (_Float16)x[j];
    }
}

// ---------------- CSR build ----------------

__global__ void count_kernel(const int* __restrict__ ei, int* __restrict__ cnt) {
    int i = blockIdx.x * blockDim.x + threadIdx.x;
    if (i >= ETOT) return;
    int v = (i < EE) ? ei[EE + i] : (i - EE);
    atomicAdd(&cnt[v], 1);
}

#define SCH 20
__global__ __launch_bounds__(1024) void scan_kernel(const int* __restrict__ cnt,
                                                    int* __restrict__ row_ptr,
                                                    int* __restrict__ cursor) {
    __shared__ int wtot[16];
    __shared__ int woff[16];
    int t = threadIdx.x;
    int lane = t & 63;
    int wid = t >> 6;
    int base = t * SCH;
    int vals[SCH];
    int s = 0;
    #pragma unroll
    for (int i = 0; i < SCH; i++) {
        int idx = base + i;
        int v = (idx < NN) ? cnt[idx] : 0;
        vals[i] = v;
        s += v;
    }
    int incl = s;
    #pragma unroll
    for (int off = 1; off < 64; off <<= 1) {
        int u = __shfl_up(incl, off);
        if (lane >= off) incl += u;
    }
    int excl = incl - s;
    if (lane == 63) wtot[wid] = incl;
    __syncthreads();
    if (t == 0) {
        int run = 0;
        #pragma unroll
        for (int j = 0; j < 16; j++) { woff[j] = run; run += wtot[j]; }
        row_ptr[NN] = run;
    }
    __syncthreads();
    int run = woff[wid] + excl;
    #pragma unroll
    for (int i = 0; i < SCH; i++) {
        int idx = base + i;
        if (idx < NN) { row_ptr[idx] = run; cursor[idx] = run; run += vals[i]; }
    }
}

__global__ void fill_kernel(const int* __restrict__ ei, int* __restrict__ cursor,
                            int* __restrict__ csr_src) {
    int i = blockIdx.x * blockDim.x + threadIdx.x;
    if (i >= ETOT) return;
    int u, v;
    if (i < EE) { u = ei[i]; v = ei[EE + i]; }
    else        { u = i - EE; v = i - EE; }
    int pos = atomicAdd(&cursor[v], 1);
    csr_src[pos] = u;
}

// ---------------- MFMA GEMM 128x128 (layers 1 & 2): f16, 8 waves (2M x 4N), fused al epilogue ----------------
// als/ald written HEAD-MAJOR: als[h][node].
#define LDK 40
__global__ __launch_bounds__(512) void gemm_al(const _Float16* __restrict__ A,
                                               const _Float16* __restrict__ Bt,
                                               _Float16* __restrict__ C16,
                                               const float* __restrict__ a_src,
                                               const float* __restrict__ a_dst,
                                               float* __restrict__ als2,
                                               float* __restrict__ ald2,
                                               int M, int K) {
    __shared__ _Float16 sA[128 * LDK];
    __shared__ _Float16 sB[128 * LDK];
    __shared__ float psum_s[4][128];
    __shared__ float psum_d[4][128];
    int tid = threadIdx.x;
    int lane = tid & 63;
    int wid = tid >> 6;          // 0..7
    int wv_m = wid >> 2;         // 0..1 : 64-row half
    int wv_n = wid & 3;          // 0..3 : 32-col slice
    int m0 = blockIdx.x * 128, n0 = blockIdx.y * 128;
    int quad = lane >> 4;
    int l15 = lane & 15;
    int arow = tid >> 2;         // 0..127
    int ac4 = tid & 3;

    floatx4 acc[4][2] = {};

    for (int k0 = 0; k0 < K; k0 += 32) {
        {
            int gm = m0 + arow;
            int4 va;
            if (gm < M) va = *(const int4*)&A[(size_t)gm * K + k0 + ac4 * 8];
            else        va = make_int4(0, 0, 0, 0);
            *(int4*)&sA[arow * LDK + ac4 * 8] = va;
            int gn = n0 + arow;
            int4 vb = *(const int4*)&Bt[(size_t)gn * K + k0 + ac4 * 8];
            *(int4*)&sB[arow * LDK + ac4 * 8] = vb;
        }
        __syncthreads();
        half8 a[4], b[2];
        #pragma unroll
        for (int i = 0; i < 4; i++)
            a[i] = *(const half8*)&sA[(wv_m * 64 + i * 16 + l15) * LDK + quad * 8];
        #pragma unroll
        for (int j = 0; j < 2; j++)
            b[j] = *(const half8*)&sB[(wv_n * 32 + j * 16 + l15) * LDK + quad * 8];
        #pragma unroll
        for (int i = 0; i < 4; i++)
            #pragma unroll
            for (int j = 0; j < 2; j++)
                acc[i][j] = __builtin_amdgcn_mfma_f32_16x16x32_f16(a[i], b[j], acc[i][j], 0, 0, 0);
        __syncthreads();
    }
    #pragma unroll
    for (int i = 0; i < 4; i++) {
        #pragma unroll
        for (int r = 0; r < 4; r++) {
            int gm = m0 + wv_m * 64 + i * 16 + quad * 4 + r;
            if (gm < M) {
                #pragma unroll
                for (int j = 0; j < 2; j++)
                    C16[(size_t)gm * HCV + n0 + wv_n * 32 + j * 16 + l15] = (_Float16)acc[i][j][r];
            }
        }
    }
    // fused half-logit epilogue: this block covers 2 heads (128 cols); wave covers 32 cols
    // of head hh = h0 + (wv_n>>1).
    int h0 = n0 >> 6;
    int hh = h0 + (wv_n >> 1);
    float as_v[2], ad_v[2];
    #pragma unroll
    for (int j = 0; j < 2; j++) {
        int dim = (wv_n * 32 + j * 16 + l15) & 63;
        as_v[j] = a_src[hh * HID + dim];
        ad_v[j] = a_dst[hh * HID + dim];
    }
    #pragma unroll
    for (int i = 0; i < 4; i++) {
        #pragma unroll
        for (int r = 0; r < 4; r++) {
            float ps = acc[i][0][r] * as_v[0] + acc[i][1][r] * as_v[1];
            float pd = acc[i][0][r] * ad_v[0] + acc[i][1][r] * ad_v[1];
            #pragma unroll
            for (int off = 1; off <= 8; off <<= 1) {
                ps += __shfl_xor(ps, off);
                pd += __shfl_xor(pd, off);
            }
            if (l15 == 0) {
                int row = wv_m * 64 + i * 16 + quad * 4 + r;   // 0..127
                psum_s[wv_n][row] = ps;
                psum_d[wv_n][row] = pd;
            }
        }
    }
    __syncthreads();
    if (tid < 128) {
        int gm = m0 + tid;
        if (gm < M) {
            als2[(size_t)h0 * NN + gm]       = psum_s[0][tid] + psum_s[1][tid];
            als2[(size_t)(h0 + 1) * NN + gm] = psum_s[2][tid] + psum_s[3][tid];
            ald2[(size_t)h0 * NN + gm]       = psum_d[0][tid] + psum_d[1][tid];
            ald2[(size_t)(h0 + 1) * NN + gm] = psum_d[2][tid] + psum_d[3][tid];
        }
    }
}

// ---------------- MFMA GEMM 64x128 (layer 3): f16 C out, fused al3 ----------------
__global__ __launch_bounds__(256) void gemm3(const _Float16* __restrict__ A,
                                             const _Float16* __restrict__ Bt,
                                             _Float16* __restrict__ C16,
                                             const float* __restrict__ a_src,
                                             const float* __restrict__ a_dst,
                                             float* __restrict__ als,
                                             float* __restrict__ ald,
                                             int M, int K) {
    __shared__ _Float16 sA[64 * LDK];
    __shared__ _Float16 sB[128 * LDK];
    __shared__ float psum_s[4][64];
    __shared__ float psum_d[4][64];
    int tid = threadIdx.x;
    int lane = tid & 63;
    int wv = tid >> 6;
    int m0 = blockIdx.x * 64;
    int quad = lane >> 4;
    int l15 = lane & 15;
    int arow = tid >> 2;
    int ac4 = tid & 3;

    floatx4 acc[4][2] = {};

    for (int k0 = 0; k0 < K; k0 += 32) {
        {
            int gm = m0 + arow;
            int4 va;
            if (gm < M && arow < 64) va = *(const int4*)&A[(size_t)gm * K + k0 + ac4 * 8];
            else                     va = make_int4(0, 0, 0, 0);
            if (arow < 64) *(int4*)&sA[arow * LDK + ac4 * 8] = va;
            #pragma unroll
            for (int r = 0; r < 2; r++) {
                int gn = arow + r * 64;
                int4 vb = *(const int4*)&Bt[(size_t)gn * K + k0 + ac4 * 8];
                *(int4*)&sB[(arow + r * 64) * LDK + ac4 * 8] = vb;
            }
        }
        __syncthreads();
        half8 a[4], b[2];
        #pragma unroll
        for (int i = 0; i < 4; i++)
            a[i] = *(const half8*)&sA[(i * 16 + l15) * LDK + quad * 8];
        #pragma unroll
        for (int j = 0; j < 2; j++)
            b[j] = *(const half8*)&sB[(wv * 32 + j * 16 + l15) * LDK + quad * 8];
        #pragma unroll
        for (int i = 0; i < 4; i++)
            #pragma unroll
            for (int j = 0; j < 2; j++)
                acc[i][j] = __builtin_amdgcn_mfma_f32_16x16x32_f16(a[i], b[j], acc[i][j], 0, 0, 0);
        __syncthreads();
    }
    #pragma unroll
    for (int i = 0; i < 4; i++) {
        #pragma unroll
        for (int r = 0; r < 4; r++) {
            int gm = m0 + i * 16 + quad * 4 + r;
            if (gm < M) {
                #pragma unroll
                for (int j = 0; j < 2; j++)
                    C16[(size_t)gm * OUTD + wv * 32 + j * 16 + l15] = (_Float16)acc[i][j][r];
            }
        }
    }
    float as_v[2], ad_v[2];
    #pragma unroll
    for (int j = 0; j < 2; j++) {
        as_v[j] = a_src[wv * 32 + j * 16 + l15];
        ad_v[j] = a_dst[wv * 32 + j * 16 + l15];
    }
    #pragma unroll
    for (int i = 0; i < 4; i++) {
        #pragma unroll
        for (int r = 0; r < 4; r++) {
            float ps = acc[i][0][r] * as_v[0] + acc[i][1][r] * as_v[1];
            float pd = acc[i][0][r] * ad_v[0] + acc[i][1][r] * ad_v[1];
            #pragma unroll
            for (int off = 1; off <= 8; off <<= 1) {
                ps += __shfl_xor(ps, off);
                pd += __shfl_xor(pd, off);
            }
            if (l15 == 0) {
                int row = i * 16 + quad * 4 + r;
                psum_s[wv][row] = ps;
                psum_d[wv][row] = pd;
            }
        }
    }
    __syncthreads();
    if (tid < 64) {
        int gm = m0 + tid;
        if (gm < M) {
            als[gm] = psum_s[0][tid] + psum_s[1][tid] + psum_s[2][tid] + psum_s[3][tid];
            ald[gm] = psum_d[0][tid] + psum_d[1][tid] + psum_d[2][tid] + psum_d[3][tid];
        }
    }
}

// ---------------- gather (layers 1 & 2): wave = (1 head, 8 nodes), 8 lanes per node ----------------
// head = blockIdx.x & 7 keeps the per-XCD working set at one head slice (2.56 MB h + 80 KB
// als2) -> L2-resident. Each 8-lane subgroup OWNS one node: walks its edge list (4-edge
// unroll for MLP), loads the 128B head-slice per edge as half8 (16B/lane, coalesced),
// accumulates 64 dims in-register. No cross-lane reduction; epilogue = bias + ELU.
__global__ __launch_bounds__(256) void gather_kernel(const _Float16* __restrict__ h,
                                                     const int* __restrict__ row_ptr,
                                                     const int* __restrict__ csr_src,
                                                     const float* __restrict__ als2,
                                                     const float* __restrict__ ald2,
                                                     const float* __restrict__ bias,
                                                     _Float16* __restrict__ gout) {
    int tid = threadIdx.x;
    int lane = tid & 63;
    int wid = tid >> 6;
    int bid = blockIdx.x;
    int hd = bid & 7;                    // head == XCD (round-robin)
    int sub = lane >> 3;                 // node slot 0..7
    int dl = lane & 7;                   // dim octet within the head
    int v = (bid >> 3) * 32 + wid * 8 + sub;
    if (v >= NN) return;
    const float* asl = als2 + (size_t)hd * NN;
    float adst = ald2[(size_t)hd * NN + v];
    int s0 = row_ptr[v], s1 = row_ptr[v + 1];
    const _Float16* hh = h + hd * HID + dl * 8;
    float acc[8] = {};
    float l = 0.f;
    int j = s0;
    for (; j + 4 <= s1; j += 4) {
        int u[4]; float p[4]; half8 xv[4];
        #pragma unroll
        for (int e = 0; e < 4; e++) u[e] = csr_src[j + e];
        #pragma unroll
        for (int e = 0; e < 4; e++) xv[e] = *(const half8*)&hh[(size_t)u[e] * HCV];
        #pragma unroll
        for (int e = 0; e < 4; e++) {
            float t = asl[u[e]] + adst;
            t = (t > 0.f) ? t : NEG_SLOPE * t;
            p[e] = __expf(fminf(t, 80.f));
        }
        #pragma unroll
        for (int e = 0; e < 4; e++) {
            l += p[e];
            #pragma unroll
            for (int k = 0; k < 8; k++)
                acc[k] = fmaf(p[e], (float)xv[e][k], acc[k]);
        }
    }
    for (; j < s1; j++) {
        int u0 = csr_src[j];
        half8 x0 = *(const half8*)&hh[(size_t)u0 * HCV];
        float t0 = asl[u0] + adst;
        t0 = (t0 > 0.f) ? t0 : NEG_SLOPE * t0;
        float p0 = __expf(fminf(t0, 80.f));
        l += p0;
        #pragma unroll
        for (int k = 0; k < 8; k++)
            acc[k] = fmaf(p0, (float)x0[k], acc[k]);
    }
    float inv = 1.f / (l + 1e-16f);
    half8 hv;
    #pragma unroll
    for (int k = 0; k < 8; k++) {
        float o = fmaf(acc[k], inv, bias[hd * HID + dl * 8 + k]);
        o = (o > 0.f) ? o : (__expf(o) - 1.f);   // ELU
        hv[k] = (_Float16)o;
    }
    half8* dst = (half8*)&gout[(size_t)v * HCV + hd * HID + dl * 8];
    __builtin_nontemporal_store(hv, dst);
}

// ---------------- layer-3 gather: wave = (1 dim-half, 8 nodes), 8 lanes per node ----------------
// dim-half = blockIdx.x & 1 -> even XCDs own dims 0..63, odd XCDs own 64..127; per-XCD
// working set = 2.56 MB h3 slice + 1.36 MB csr + 80 KB als -> ~L2-resident. Each 8-lane
// subgroup owns one node: redundant-scalar max pass, then accumulate pass with exp(t-m).
__global__ __launch_bounds__(256) void gather3_kernel(const _Float16* __restrict__ h,
                                                      const int* __restrict__ row_ptr,
                                                      const int* __restrict__ csr_src,
                                                      const float* __restrict__ als,
                                                      const float* __restrict__ ald,
                                                      const float* __restrict__ bias,
                                                      float* __restrict__ out) {
    int tid = threadIdx.x;
    int lane = tid & 63;
    int wid = tid >> 6;
    int bid = blockIdx.x;
    int dh = bid & 1;                    // dim-half (XCD parity)
    int sub = lane >> 3;                 // node slot 0..7
    int dl = lane & 7;                   // dim octet within the half
    int v = (bid >> 1) * 32 + wid * 8 + sub;
    if (v >= NN) return;
    float adst = ald[v];
    int s0 = row_ptr[v], s1 = row_ptr[v + 1];
    const _Float16* hh = h + dh * 64 + dl * 8;
    // pass 1: max (redundant across the 8 lanes, scalar walk)
    float m = -INFINITY;
    for (int j = s0; j < s1; j++) {
        int u = csr_src[j];
        float t = als[u] + adst;
        t = (t > 0.f) ? t : NEG_SLOPE * t;
        m = fmaxf(m, t);
    }
    // pass 2: accumulate
    float acc[8] = {};
    float l = 0.f;
    int j = s0;
    for (; j + 2 <= s1; j += 2) {
        int u0 = csr_src[j], u1 = csr_src[j + 1];
        float t0 = als[u0] + adst;
        float t1 = als[u1] + adst;
        t0 = (t0 > 0.f) ? t0 : NEG_SLOPE * t0;
        t1 = (t1 > 0.f) ? t1 : NEG_SLOPE * t1;
        float p0 = __expf(t0 - m);
        float p1 = __expf(t1 - m);
        half8 x0 = *(const half8*)&hh[(size_t)u0 * OUTD];
        half8 x1 = *(const half8*)&hh[(size_t)u1 * OUTD];
        l += p0 + p1;
        #pragma unroll
        for (int k = 0; k < 8; k++) {
            acc[k] = fmaf(p0, (float)x0[k], acc[k]);
            acc[k] = fmaf(p1, (float)x1[k], acc[k]);
        }
    }
    if (j < s1) {
        int u0 = csr_src[j];
        float t0 = als[u0] + adst;
        t0 = (t0 > 0.f) ? t0 : NEG_SLOPE * t0;
        float p0 = __expf(t0 - m);
        half8 x0 = *(const half8*)&hh[(size_t)u0 * OUTD];
        l += p0;
        #pragma unroll
        for (int k = 0; k < 8; k++)
            acc[k] = fmaf(p0, (float)x0[k], acc[k]);
    }
    float inv = 1.f / (l + 1e-16f);
    float4 o0, o1;
    o0.x = fmaf(acc[0], inv, bias[dh * 64 + dl * 8 + 0]);
    o0.y = fmaf(acc[1], inv, bias[dh * 64 + dl * 8 + 1]);
    o0.z = fmaf(acc[2], inv, bias[dh * 64 + dl * 8 + 2]);
    o0.w = fmaf(acc[3], inv, bias[dh * 64 + dl * 8 + 3]);
    o1.x = fmaf(acc[4], inv, bias[dh * 64 + dl * 8 + 4]);
    o1.y = fmaf(acc[5], inv, bias[dh * 64 + dl * 8 + 5]);
    o1.z = fmaf(acc[6], inv, bias[dh * 64 + dl * 8 + 6]);
    o1.w = fmaf(acc[7], inv, bias[dh * 64 + dl * 8 + 7]);
    size_t base = (size_t)v * OUTD + dh * 64 + dl * 8;
    *(float4*)&out[base] = o0;
    *(float4*)&out[base + 4] = o1;
}

// ---------------- launch ----------------

extern "C" void kernel_launch(void* const* d_in, const int* in_sizes, int n_in,
                              void* d_out, int out_size, void* d_ws, size_t ws_size,
                              hipStream_t stream) {
    const float* x     = (const float*)d_in[0];
    const int*   ei    = (const int*)d_in[1];
    const float* W1    = (const float*)d_in[2];
    const float* as1   = (const float*)d_in[3];
    const float* ad1   = (const float*)d_in[4];
    const float* b1    = (const float*)d_in[5];
    const float* W2    = (const float*)d_in[6];
    const float* as2   = (const float*)d_in[7];
    const float* ad2   = (const float*)d_in[8];
    const float* b2    = (const float*)d_in[9];
    const float* W3    = (const float*)d_in[10];
    const float* as3   = (const float*)d_in[11];
    const float* ad3   = (const float*)d_in[12];
    const float* b3    = (const float*)d_in[13];
    float* out = (float*)d_out;

    size_t off = 0;
    auto carve = [&](size_t bytes) {
        void* p = (char*)d_ws + off;
        off += (bytes + 255) & ~(size_t)255;
        return p;
    };
    int* row_ptr   = (int*)carve((NN + 1) * sizeof(int));
    int* cursor    = (int*)carve(NN * sizeof(int));
    int* csr_src   = (int*)carve(ETOT * sizeof(int));
    _Float16* xh   = (_Float16*)carve((size_t)NN * IND * sizeof(_Float16));
    _Float16* h1   = (_Float16*)carve((size_t)NN * HCV * sizeof(_Float16));
    _Float16* gact = (_Float16*)carve((size_t)NN * HCV * sizeof(_Float16));
    _Float16* hf16 = (_Float16*)carve((size_t)NN * HCV * sizeof(_Float16));
    _Float16* h3   = (_Float16*)carve((size_t)NN * OUTD * sizeof(_Float16));
    float* als     = (float*)carve((size_t)NN * NHEADS * sizeof(float));
    float* ald     = (float*)carve((size_t)NN * NHEADS * sizeof(float));
    _Float16* W1T  = (_Float16*)carve((size_t)S1 * sizeof(_Float16));
    _Float16* W2T  = (_Float16*)carve((size_t)S2 * sizeof(_Float16));
    _Float16* W3T  = (_Float16*)carve((size_t)S3 * sizeof(_Float16));
    _Float16* gact2 = h1;   // aliases h1 (dead after layer-1 gather)
    (void)ws_size; (void)n_in; (void)in_sizes; (void)out_size;

    dim3 blk(256);

    // ---- prep ----
    int prep_n = STOT + NN + XTOT;
    prep_kernel<<<(prep_n + 255) / 256, blk, 0, stream>>>(W1, W2, W3, x,
        W1T, W2T, W3T, xh, cursor);

    // ---- CSR build ----
    count_kernel<<<(ETOT + 255) / 256, blk, 0, stream>>>(ei, cursor);
    scan_kernel<<<1, 1024, 0, stream>>>(cursor, row_ptr, cursor);
    fill_kernel<<<(ETOT + 255) / 256, blk, 0, stream>>>(ei, cursor, csr_src);

    int mt64 = (NN + 63) / 64;
    int mt128 = (NN + 127) / 128;
    int nb = (NN + 31) / 32;   // node-blocks per head/half for gathers (4 waves x 8 nodes)

    // ---- layer 1: project-first (dense GEMM + fused al), then head-sliced gather ----
    gemm_al<<<dim3(mt128, HCV / 128), dim3(512), 0, stream>>>(xh, W1T, h1, as1, ad1, als, ald, NN, IND);
    gather_kernel<<<dim3(nb * 8), blk, 0, stream>>>(h1, row_ptr, csr_src, als, ald, b1, gact);

    // ---- layer 2: identical structure ----
    gemm_al<<<dim3(mt128, HCV / 128), dim3(512), 0, stream>>>(gact, W2T, hf16, as2, ad2, als, ald, NN, HCV);
    gather_kernel<<<dim3(nb * 8), blk, 0, stream>>>(hf16, row_ptr, csr_src, als, ald, b2, gact2);

    // ---- layer 3: output-side, fp16 h3, dim-half sliced gather ----
    gemm3<<<dim3(mt64, 1), blk, 0, stream>>>(gact2, W3T, h3, as3, ad3, als, ald, NN, HCV);
    gather3_kernel<<<dim3(nb * 2), blk, 0, stream>>>(h3, row_ptr, csr_src, als, ald, b3, out);
}

// Round 6
// 310.135 us; speedup vs baseline: 1.2375x; 1.0076x over previous
//
#include <hip/hip_runtime.h>
#include <math.h>

#define NN 20000
#define EE 320000
#define ETOT 340000   // EE + NN self-loops
#define NHEADS 8
#define HID 64
#define HCV 512       // NHEADS*HID
#define IND 128
#define OUTD 128
#define NEG_SLOPE 0.2f
#define LOG2E 1.4426950408889634f

typedef __attribute__((ext_vector_type(8))) _Float16 half8;
typedef __attribute__((ext_vector_type(4))) _Float16 half4;
typedef __attribute__((ext_vector_type(4))) float floatx4;

#define S1 (IND * HCV)
#define S2 (HCV * HCV)
#define S3 (HCV * OUTD)
#define XTOT (NN * IND)

// ---------------- prep: LDS-tiled W transposes + vectorized x cvt + zero cnt ----------------
// tiles: W1 (128x512) -> 64, W2 (512x512) -> 256, W3 (512x128) -> 64. Then x-cvt float4
// blocks (2500), then cnt-zero blocks (79).
#define NT1 64
#define NT2 320      // 64 + 256
#define NT_TOT 384
#define XB 2500      // XTOT/1024
__global__ __launch_bounds__(256) void prep_kernel(const float* __restrict__ W1,
                                                   const float* __restrict__ W2,
                                                   const float* __restrict__ W3,
                                                   const float* __restrict__ x,
                                                   _Float16* __restrict__ T1,
                                                   _Float16* __restrict__ T2,
                                                   _Float16* __restrict__ T3,
                                                   _Float16* __restrict__ xh,
                                                   int* __restrict__ cnt) {
    int b = blockIdx.x;
    int tid = threadIdx.x;
    if (b < NT_TOT) {
        __shared__ _Float16 tile[32][34];
        const float* W; _Float16* T; int K, N, tb;
        if (b < NT1)      { W = W1; T = T1; K = IND; N = HCV;  tb = b; }
        else if (b < NT2) { W = W2; T = T2; K = HCV; N = HCV;  tb = b - NT1; }
        else              { W = W3; T = T3; K = HCV; N = OUTD; tb = b - NT2; }
        int ntn = N >> 5;
        int k0 = (tb / ntn) * 32, n0 = (tb % ntn) * 32;
        int tx = tid & 31, ty0 = tid >> 5;
        #pragma unroll
        for (int i = 0; i < 4; i++) {
            int ty = ty0 + 8 * i;
            tile[ty][tx] = (_Float16)W[(size_t)(k0 + ty) * N + n0 + tx];
        }
        __syncthreads();
        #pragma unroll
        for (int i = 0; i < 4; i++) {
            int ty = ty0 + 8 * i;
            T[(size_t)(n0 + ty) * K + k0 + tx] = tile[tx][ty];
        }
    } else if (b < NT_TOT + XB) {
        int idx = (b - NT_TOT) * 256 + tid;          // float4 index
        int j = idx * 4;
        float4 v = *(const float4*)&x[j];
        half4 o;
        o[0] = (_Float16)v.x; o[1] = (_Float16)v.y;
        o[2] = (_Float16)v.z; o[3] = (_Float16)v.w;
        *(half4*)&xh[j] = o;
    } else {
        int idx = (b - NT_TOT - XB) * 256 + tid;
        if (idx < NN) cnt[idx] = 0;
    }
}

// ---------------- CSR build ----------------

__global__ void count_kernel(const int* __restrict__ ei, int* __restrict__ cnt) {
    int i = blockIdx.x * blockDim.x + threadIdx.x;
    if (i >= ETOT) return;
    int v = (i < EE) ? ei[EE + i] : (i - EE);
    atomicAdd(&cnt[v], 1);
}

#define SCH 20
__global__ __launch_bounds__(1024) void scan_kernel(const int* __restrict__ cnt,
                                                    int* __restrict__ row_ptr,
                                                    int* __restrict__ cursor) {
    __shared__ int wtot[16];
    __shared__ int woff[16];
    int t = threadIdx.x;
    int lane = t & 63;
    int wid = t >> 6;
    int base = t * SCH;
    int vals[SCH];
    int s = 0;
    #pragma unroll
    for (int i = 0; i < SCH; i++) {
        int idx = base + i;
        int v = (idx < NN) ? cnt[idx] : 0;
        vals[i] = v;
        s += v;
    }
    int incl = s;
    #pragma unroll
    for (int off = 1; off < 64; off <<= 1) {
        int u = __shfl_up(incl, off);
        if (lane >= off) incl += u;
    }
    int excl = incl - s;
    if (lane == 63) wtot[wid] = incl;
    __syncthreads();
    if (t == 0) {
        int run = 0;
        #pragma unroll
        for (int j = 0; j < 16; j++) { woff[j] = run; run += wtot[j]; }
        row_ptr[NN] = run;
    }
    __syncthreads();
    int run = woff[wid] + excl;
    #pragma unroll
    for (int i = 0; i < SCH; i++) {
        int idx = base + i;
        if (idx < NN) { row_ptr[idx] = run; cursor[idx] = run; run += vals[i]; }
    }
}

__global__ void fill_kernel(const int* __restrict__ ei, int* __restrict__ cursor,
                            int* __restrict__ csr_src) {
    int i = blockIdx.x * blockDim.x + threadIdx.x;
    if (i >= ETOT) return;
    int u, v;
    if (i < EE) { u = ei[i]; v = ei[EE + i]; }
    else        { u = i - EE; v = i - EE; }
    int pos = atomicAdd(&cursor[v], 1);
    csr_src[pos] = u;
}

// ---------------- MFMA GEMM 128x128 (layers 1 & 2): f16, 8 waves (2M x 4N), fused al epilogue ----------------
// als/ald written HEAD-MAJOR (als[h][node]) and PRESCALED by log2(e) for exp2 in gathers.
#define LDK 40
__global__ __launch_bounds__(512) void gemm_al(const _Float16* __restrict__ A,
                                               const _Float16* __restrict__ Bt,
                                               _Float16* __restrict__ C16,
                                               const float* __restrict__ a_src,
                                               const float* __restrict__ a_dst,
                                               float* __restrict__ als2,
                                               float* __restrict__ ald2,
                                               int M, int K) {
    __shared__ _Float16 sA[128 * LDK];
    __shared__ _Float16 sB[128 * LDK];
    __shared__ float psum_s[4][128];
    __shared__ float psum_d[4][128];
    int tid = threadIdx.x;
    int lane = tid & 63;
    int wid = tid >> 6;          // 0..7
    int wv_m = wid >> 2;         // 0..1 : 64-row half
    int wv_n = wid & 3;          // 0..3 : 32-col slice
    int m0 = blockIdx.x * 128, n0 = blockIdx.y * 128;
    int quad = lane >> 4;
    int l15 = lane & 15;
    int arow = tid >> 2;         // 0..127
    int ac4 = tid & 3;

    floatx4 acc[4][2] = {};

    for (int k0 = 0; k0 < K; k0 += 32) {
        {
            int gm = m0 + arow;
            int4 va;
            if (gm < M) va = *(const int4*)&A[(size_t)gm * K + k0 + ac4 * 8];
            else        va = make_int4(0, 0, 0, 0);
            *(int4*)&sA[arow * LDK + ac4 * 8] = va;
            int gn = n0 + arow;
            int4 vb = *(const int4*)&Bt[(size_t)gn * K + k0 + ac4 * 8];
            *(int4*)&sB[arow * LDK + ac4 * 8] = vb;
        }
        __syncthreads();
        half8 a[4], b[2];
        #pragma unroll
        for (int i = 0; i < 4; i++)
            a[i] = *(const half8*)&sA[(wv_m * 64 + i * 16 + l15) * LDK + quad * 8];
        #pragma unroll
        for (int j = 0; j < 2; j++)
            b[j] = *(const half8*)&sB[(wv_n * 32 + j * 16 + l15) * LDK + quad * 8];
        #pragma unroll
        for (int i = 0; i < 4; i++)
            #pragma unroll
            for (int j = 0; j < 2; j++)
                acc[i][j] = __builtin_amdgcn_mfma_f32_16x16x32_f16(a[i], b[j], acc[i][j], 0, 0, 0);
        __syncthreads();
    }
    #pragma unroll
    for (int i = 0; i < 4; i++) {
        #pragma unroll
        for (int r = 0; r < 4; r++) {
            int gm = m0 + wv_m * 64 + i * 16 + quad * 4 + r;
            if (gm < M) {
                #pragma unroll
                for (int j = 0; j < 2; j++)
                    C16[(size_t)gm * HCV + n0 + wv_n * 32 + j * 16 + l15] = (_Float16)acc[i][j][r];
            }
        }
    }
    // fused half-logit epilogue (prescaled by log2e)
    int h0 = n0 >> 6;
    int hh = h0 + (wv_n >> 1);
    float as_v[2], ad_v[2];
    #pragma unroll
    for (int j = 0; j < 2; j++) {
        int dim = (wv_n * 32 + j * 16 + l15) & 63;
        as_v[j] = a_src[hh * HID + dim] * LOG2E;
        ad_v[j] = a_dst[hh * HID + dim] * LOG2E;
    }
    #pragma unroll
    for (int i = 0; i < 4; i++) {
        #pragma unroll
        for (int r = 0; r < 4; r++) {
            float ps = acc[i][0][r] * as_v[0] + acc[i][1][r] * as_v[1];
            float pd = acc[i][0][r] * ad_v[0] + acc[i][1][r] * ad_v[1];
            #pragma unroll
            for (int off = 1; off <= 8; off <<= 1) {
                ps += __shfl_xor(ps, off);
                pd += __shfl_xor(pd, off);
            }
            if (l15 == 0) {
                int row = wv_m * 64 + i * 16 + quad * 4 + r;   // 0..127
                psum_s[wv_n][row] = ps;
                psum_d[wv_n][row] = pd;
            }
        }
    }
    __syncthreads();
    if (tid < 128) {
        int gm = m0 + tid;
        if (gm < M) {
            als2[(size_t)h0 * NN + gm]       = psum_s[0][tid] + psum_s[1][tid];
            als2[(size_t)(h0 + 1) * NN + gm] = psum_s[2][tid] + psum_s[3][tid];
            ald2[(size_t)h0 * NN + gm]       = psum_d[0][tid] + psum_d[1][tid];
            ald2[(size_t)(h0 + 1) * NN + gm] = psum_d[2][tid] + psum_d[3][tid];
        }
    }
}

// ---------------- MFMA GEMM 64x128 (layer 3): f16 C out, fused al3 (prescaled) ----------------
__global__ __launch_bounds__(256) void gemm3(const _Float16* __restrict__ A,
                                             const _Float16* __restrict__ Bt,
                                             _Float16* __restrict__ C16,
                                             const float* __restrict__ a_src,
                                             const float* __restrict__ a_dst,
                                             float* __restrict__ als,
                                             float* __restrict__ ald,
                                             int M, int K) {
    __shared__ _Float16 sA[64 * LDK];
    __shared__ _Float16 sB[128 * LDK];
    __shared__ float psum_s[4][64];
    __shared__ float psum_d[4][64];
    int tid = threadIdx.x;
    int lane = tid & 63;
    int wv = tid >> 6;
    int m0 = blockIdx.x * 64;
    int quad = lane >> 4;
    int l15 = lane & 15;
    int arow = tid >> 2;
    int ac4 = tid & 3;

    floatx4 acc[4][2] = {};

    for (int k0 = 0; k0 < K; k0 += 32) {
        {
            int gm = m0 + arow;
            int4 va;
            if (gm < M && arow < 64) va = *(const int4*)&A[(size_t)gm * K + k0 + ac4 * 8];
            else                     va = make_int4(0, 0, 0, 0);
            if (arow < 64) *(int4*)&sA[arow * LDK + ac4 * 8] = va;
            #pragma unroll
            for (int r = 0; r < 2; r++) {
                int gn = arow + r * 64;
                int4 vb = *(const int4*)&Bt[(size_t)gn * K + k0 + ac4 * 8];
                *(int4*)&sB[(arow + r * 64) * LDK + ac4 * 8] = vb;
            }
        }
        __syncthreads();
        half8 a[4], b[2];
        #pragma unroll
        for (int i = 0; i < 4; i++)
            a[i] = *(const half8*)&sA[(i * 16 + l15) * LDK + quad * 8];
        #pragma unroll
        for (int j = 0; j < 2; j++)
            b[j] = *(const half8*)&sB[(wv * 32 + j * 16 + l15) * LDK + quad * 8];
        #pragma unroll
        for (int i = 0; i < 4; i++)
            #pragma unroll
            for (int j = 0; j < 2; j++)
                acc[i][j] = __builtin_amdgcn_mfma_f32_16x16x32_f16(a[i], b[j], acc[i][j], 0, 0, 0);
        __syncthreads();
    }
    #pragma unroll
    for (int i = 0; i < 4; i++) {
        #pragma unroll
        for (int r = 0; r < 4; r++) {
            int gm = m0 + i * 16 + quad * 4 + r;
            if (gm < M) {
                #pragma unroll
                for (int j = 0; j < 2; j++)
                    C16[(size_t)gm * OUTD + wv * 32 + j * 16 + l15] = (_Float16)acc[i][j][r];
            }
        }
    }
    float as_v[2], ad_v[2];
    #pragma unroll
    for (int j = 0; j < 2; j++) {
        as_v[j] = a_src[wv * 32 + j * 16 + l15] * LOG2E;
        ad_v[j] = a_dst[wv * 32 + j * 16 + l15] * LOG2E;
    }
    #pragma unroll
    for (int i = 0; i < 4; i++) {
        #pragma unroll
        for (int r = 0; r < 4; r++) {
            float ps = acc[i][0][r] * as_v[0] + acc[i][1][r] * as_v[1];
            float pd = acc[i][0][r] * ad_v[0] + acc[i][1][r] * ad_v[1];
            #pragma unroll
            for (int off = 1; off <= 8; off <<= 1) {
                ps += __shfl_xor(ps, off);
                pd += __shfl_xor(pd, off);
            }
            if (l15 == 0) {
                int row = i * 16 + quad * 4 + r;
                psum_s[wv][row] = ps;
                psum_d[wv][row] = pd;
            }
        }
    }
    __syncthreads();
    if (tid < 64) {
        int gm = m0 + tid;
        if (gm < M) {
            als[gm] = psum_s[0][tid] + psum_s[1][tid] + psum_s[2][tid] + psum_s[3][tid];
            ald[gm] = psum_d[0][tid] + psum_d[1][tid] + psum_d[2][tid] + psum_d[3][tid];
        }
    }
}

// ---------------- gather (layers 1 & 2): wave = (1 head, 4 nodes x 2 walkers), 8 dim-lanes ----------------
// head = blockIdx.x & 7 -> per-XCD working set = one head slice (2.56 MB h + 80 KB als).
// Each node owned by a 16-lane group: 2 edge-walkers (range-split) x 8 dim-lanes; halves the
// serial edge chain and the degree imbalance. Combine via shfl_xor(8). Logits prescaled ->
// exp2f. Epilogue bias + ELU, nontemporal store.
__global__ __launch_bounds__(256) void gather_kernel(const _Float16* __restrict__ h,
                                                     const int* __restrict__ row_ptr,
                                                     const int* __restrict__ csr_src,
                                                     const float* __restrict__ als2,
                                                     const float* __restrict__ ald2,
                                                     const float* __restrict__ bias,
                                                     _Float16* __restrict__ gout) {
    int tid = threadIdx.x;
    int lane = tid & 63;
    int wid = tid >> 6;
    int bid = blockIdx.x;
    int hd = bid & 7;                    // head == XCD (round-robin)
    int dl = lane & 7;                   // dim octet within the head
    int es = (lane >> 3) & 1;            // edge-walker slot
    int sub = lane >> 4;                 // node slot 0..3
    int v = (bid >> 3) * 16 + wid * 4 + sub;
    if (v >= NN) return;
    const float* asl = als2 + (size_t)hd * NN;
    float adst = ald2[(size_t)hd * NN + v];
    int s0 = row_ptr[v], s1 = row_ptr[v + 1];
    int mid = (s0 + s1 + 1) >> 1;
    int jb = es ? mid : s0;
    int je = es ? s1 : mid;
    const _Float16* hh = h + hd * HID + dl * 8;
    float acc[8] = {};
    float l = 0.f;
    int j = jb;
    for (; j + 4 <= je; j += 4) {
        int u[4]; float p[4]; half8 xv[4];
        #pragma unroll
        for (int e = 0; e < 4; e++) u[e] = csr_src[j + e];
        #pragma unroll
        for (int e = 0; e < 4; e++) xv[e] = *(const half8*)&hh[(size_t)u[e] * HCV];
        #pragma unroll
        for (int e = 0; e < 4; e++) {
            float t = asl[u[e]] + adst;
            t = (t > 0.f) ? t : NEG_SLOPE * t;
            p[e] = exp2f(fminf(t, 115.f));
        }
        #pragma unroll
        for (int e = 0; e < 4; e++) {
            l += p[e];
            #pragma unroll
            for (int k = 0; k < 8; k++)
                acc[k] = fmaf(p[e], (float)xv[e][k], acc[k]);
        }
    }
    for (; j < je; j++) {
        int u0 = csr_src[j];
        half8 x0 = *(const half8*)&hh[(size_t)u0 * HCV];
        float t0 = asl[u0] + adst;
        t0 = (t0 > 0.f) ? t0 : NEG_SLOPE * t0;
        float p0 = exp2f(fminf(t0, 115.f));
        l += p0;
        #pragma unroll
        for (int k = 0; k < 8; k++)
            acc[k] = fmaf(p0, (float)x0[k], acc[k]);
    }
    // combine the two walkers (lanes differ only in bit 3)
    l += __shfl_xor(l, 8);
    #pragma unroll
    for (int k = 0; k < 8; k++)
        acc[k] += __shfl_xor(acc[k], 8);
    if (es == 0) {
        float inv = 1.f / (l + 1e-16f);
        half8 hv;
        #pragma unroll
        for (int k = 0; k < 8; k++) {
            float o = fmaf(acc[k], inv, bias[hd * HID + dl * 8 + k]);
            o = (o > 0.f) ? o : (__expf(o) - 1.f);   // ELU
            hv[k] = (_Float16)o;
        }
        half8* dst = (half8*)&gout[(size_t)v * HCV + hd * HID + dl * 8];
        __builtin_nontemporal_store(hv, dst);
    }
}

// ---------------- layer-3 gather: wave = (1 dim-half, 4 nodes x 2 walkers) ----------------
// dim-half = blockIdx.x & 1 (XCD parity) -> 2.56 MB h3 slice per XCD. Max pass: 16-lane
// strided walk + shfl_xor reduce. Accumulate: 2 range-split walkers, shfl_xor(8) combine.
__global__ __launch_bounds__(256) void gather3_kernel(const _Float16* __restrict__ h,
                                                      const int* __restrict__ row_ptr,
                                                      const int* __restrict__ csr_src,
                                                      const float* __restrict__ als,
                                                      const float* __restrict__ ald,
                                                      const float* __restrict__ bias,
                                                      float* __restrict__ out) {
    int tid = threadIdx.x;
    int lane = tid & 63;
    int wid = tid >> 6;
    int bid = blockIdx.x;
    int dh = bid & 1;                    // dim-half (XCD parity)
    int dl = lane & 7;
    int es = (lane >> 3) & 1;
    int sub = lane >> 4;                 // node slot 0..3
    int l16 = lane & 15;
    int v = (bid >> 1) * 16 + wid * 4 + sub;
    if (v >= NN) return;
    float adst = ald[v];
    int s0 = row_ptr[v], s1 = row_ptr[v + 1];
    // pass 1: max over the node's edges, 16-lane parallel
    float m = -INFINITY;
    for (int j = s0 + l16; j < s1; j += 16) {
        int u = csr_src[j];
        float t = als[u] + adst;
        t = (t > 0.f) ? t : NEG_SLOPE * t;
        m = fmaxf(m, t);
    }
    #pragma unroll
    for (int off = 1; off <= 8; off <<= 1)
        m = fmaxf(m, __shfl_xor(m, off));
    // pass 2: accumulate, 2 range-split walkers
    int mid = (s0 + s1 + 1) >> 1;
    int jb = es ? mid : s0;
    int je = es ? s1 : mid;
    const _Float16* hh = h + dh * 64 + dl * 8;
    float acc[8] = {};
    float l = 0.f;
    int j = jb;
    for (; j + 2 <= je; j += 2) {
        int u0 = csr_src[j], u1 = csr_src[j + 1];
        float t0 = als[u0] + adst;
        float t1 = als[u1] + adst;
        t0 = (t0 > 0.f) ? t0 : NEG_SLOPE * t0;
        t1 = (t1 > 0.f) ? t1 : NEG_SLOPE * t1;
        float p0 = exp2f(t0 - m);
        float p1 = exp2f(t1 - m);
        half8 x0 = *(const half8*)&hh[(size_t)u0 * OUTD];
        half8 x1 = *(const half8*)&hh[(size_t)u1 * OUTD];
        l += p0 + p1;
        #pragma unroll
        for (int k = 0; k < 8; k++) {
            acc[k] = fmaf(p0, (float)x0[k], acc[k]);
            acc[k] = fmaf(p1, (float)x1[k], acc[k]);
        }
    }
    if (j < je) {
        int u0 = csr_src[j];
        float t0 = als[u0] + adst;
        t0 = (t0 > 0.f) ? t0 : NEG_SLOPE * t0;
        float p0 = exp2f(t0 - m);
        half8 x0 = *(const half8*)&hh[(size_t)u0 * OUTD];
        l += p0;
        #pragma unroll
        for (int k = 0; k < 8; k++)
            acc[k] = fmaf(p0, (float)x0[k], acc[k]);
    }
    l += __shfl_xor(l, 8);
    #pragma unroll
    for (int k = 0; k < 8; k++)
        acc[k] += __shfl_xor(acc[k], 8);
    if (es == 0) {
        float inv = 1.f / (l + 1e-16f);
        float4 o0, o1;
        o0.x = fmaf(acc[0], inv, bias[dh * 64 + dl * 8 + 0]);
        o0.y = fmaf(acc[1], inv, bias[dh * 64 + dl * 8 + 1]);
        o0.z = fmaf(acc[2], inv, bias[dh * 64 + dl * 8 + 2]);
        o0.w = fmaf(acc[3], inv, bias[dh * 64 + dl * 8 + 3]);
        o1.x = fmaf(acc[4], inv, bias[dh * 64 + dl * 8 + 4]);
        o1.y = fmaf(acc[5], inv, bias[dh * 64 + dl * 8 + 5]);
        o1.z = fmaf(acc[6], inv, bias[dh * 64 + dl * 8 + 6]);
        o1.w = fmaf(acc[7], inv, bias[dh * 64 + dl * 8 + 7]);
        size_t base = (size_t)v * OUTD + dh * 64 + dl * 8;
        *(float4*)&out[base] = o0;
        *(float4*)&out[base + 4] = o1;
    }
}

// ---------------- launch ----------------

extern "C" void kernel_launch(void* const* d_in, const int* in_sizes, int n_in,
                              void* d_out, int out_size, void* d_ws, size_t ws_size,
                              hipStream_t stream) {
    const float* x     = (const float*)d_in[0];
    const int*   ei    = (const int*)d_in[1];
    const float* W1    = (const float*)d_in[2];
    const float* as1   = (const float*)d_in[3];
    const float* ad1   = (const float*)d_in[4];
    const float* b1    = (const float*)d_in[5];
    const float* W2    = (const float*)d_in[6];
    const float* as2   = (const float*)d_in[7];
    const float* ad2   = (const float*)d_in[8];
    const float* b2    = (const float*)d_in[9];
    const float* W3    = (const float*)d_in[10];
    const float* as3   = (const float*)d_in[11];
    const float* ad3   = (const float*)d_in[12];
    const float* b3    = (const float*)d_in[13];
    float* out = (float*)d_out;

    size_t off = 0;
    auto carve = [&](size_t bytes) {
        void* p = (char*)d_ws + off;
        off += (bytes + 255) & ~(size_t)255;
        return p;
    };
    int* row_ptr   = (int*)carve((NN + 1) * sizeof(int));
    int* cursor    = (int*)carve(NN * sizeof(int));
    int* csr_src   = (int*)carve(ETOT * sizeof(int));
    _Float16* xh   = (_Float16*)carve((size_t)NN * IND * sizeof(_Float16));
    _Float16* h1   = (_Float16*)carve((size_t)NN * HCV * sizeof(_Float16));
    _Float16* gact = (_Float16*)carve((size_t)NN * HCV * sizeof(_Float16));
    _Float16* hf16 = (_Float16*)carve((size_t)NN * HCV * sizeof(_Float16));
    _Float16* h3   = (_Float16*)carve((size_t)NN * OUTD * sizeof(_Float16));
    float* als     = (float*)carve((size_t)NN * NHEADS * sizeof(float));
    float* ald     = (float*)carve((size_t)NN * NHEADS * sizeof(float));
    _Float16* W1T  = (_Float16*)carve((size_t)S1 * sizeof(_Float16));
    _Float16* W2T  = (_Float16*)carve((size_t)S2 * sizeof(_Float16));
    _Float16* W3T  = (_Float16*)carve((size_t)S3 * sizeof(_Float16));
    _Float16* gact2 = h1;   // aliases h1 (dead after layer-1 gather)
    (void)ws_size; (void)n_in; (void)in_sizes; (void)out_size;

    dim3 blk(256);

    // ---- prep (tiled transposes + x cvt + cnt zero) ----
    int prep_blocks = NT_TOT + XB + (NN + 255) / 256;
    prep_kernel<<<prep_blocks, blk, 0, stream>>>(W1, W2, W3, x, W1T, W2T, W3T, xh, cursor);

    // ---- CSR build ----
    count_kernel<<<(ETOT + 255) / 256, blk, 0, stream>>>(ei, cursor);
    scan_kernel<<<1, 1024, 0, stream>>>(cursor, row_ptr, cursor);
    fill_kernel<<<(ETOT + 255) / 256, blk, 0, stream>>>(ei, cursor, csr_src);

    int mt64 = (NN + 63) / 64;
    int mt128 = (NN + 127) / 128;
    int nb4 = (NN + 15) / 16;   // node-blocks (4 waves x 4 nodes per block)

    // ---- layer 1: project-first (dense GEMM + fused al), then head-sliced gather ----
    gemm_al<<<dim3(mt128, HCV / 128), dim3(512), 0, stream>>>(xh, W1T, h1, as1, ad1, als, ald, NN, IND);
    gather_kernel<<<dim3(nb4 * 8), blk, 0, stream>>>(h1, row_ptr, csr_src, als, ald, b1, gact);

    // ---- layer 2: identical structure ----
    gemm_al<<<dim3(mt128, HCV / 128), dim3(512), 0, stream>>>(gact, W2T, hf16, as2, ad2, als, ald, NN, HCV);
    gather_kernel<<<dim3(nb4 * 8), blk, 0, stream>>>(hf16, row_ptr, csr_src, als, ald, b2, gact2);

    // ---- layer 3: output-side, fp16 h3, dim-half sliced gather ----
    gemm3<<<dim3(mt64, 1), blk, 0, stream>>>(gact2, W3T, h3, as3, ad3, als, ald, NN, HCV);
    gather3_kernel<<<dim3(nb4 * 2), blk, 0, stream>>>(h3, row_ptr, csr_src, als, ald, b3, out);
}